// Round 6
// baseline (305.093 us; speedup 1.0000x reference)
//
#include <hip/hip_runtime.h>
#include <hip/hip_bf16.h>

// Pipeline: roi_align -> conv3x3(C=256->E=256 on 3x3 spatial, pad 1) -> GroupNorm(8)
//           -> ReLU -> spatial mean -> head GEMM -> +spat +sym_emb -> per-sid fuse matvec.
// Sizes: B=2, C=E=256, S=3, L=5, N=128, HMAX=128.
// 2 launches: prep(w_prep + t7 transposes + roi + counter zero) ->
//             conv_gn_pool_head (last block per sample runs the head+fuse epilogue).

__device__ __forceinline__ float bf_lo(unsigned u) { return __uint_as_float(u << 16); }
__device__ __forceinline__ float bf_hi(unsigned u) { return __uint_as_float(u & 0xffff0000u); }
__device__ __forceinline__ unsigned short f2bf(float f) {
    __hip_bfloat16 h = __float2bfloat16(f);
    return *(unsigned short*)&h;
}

// ---------------- fused prep kernel ----------------
// grid.x: [0,256)    w_prep (block=c, thread=e); blocks 0..127 also zero counter[n]
//         [256,704)  t7     (448 transpose tiles: head_w + 6x fuse_w)
//         [704,1856) roi    (block=(n,p), thread=c)
__global__ __launch_bounds__(256) void prep_k(
    const float* __restrict__ conv_w,
    const float* __restrict__ head_w, const float* __restrict__ fuse_w,
    const float* __restrict__ fm, const float* __restrict__ boxes,
    const int* __restrict__ batch_idx, const int* __restrict__ level_idx,
    unsigned short* __restrict__ w8, unsigned short* __restrict__ w9,
    float* __restrict__ head_wT, float* __restrict__ fuse_wT,
    float* __restrict__ roiT, int* __restrict__ counter) {
    int blk = blockIdx.x;
    int t = threadIdx.x;

    if (blk < 256) {
        if (blk < 128 && t == 0) counter[blk] = 0;   // visible to next kernel via stream order
        // conv weight repack: [e][c][9] f32 -> w8[c][e][8] + w9[c][e] bf16
        int c = blk, e = t;
        const float* src = conv_w + ((size_t)e * 256 + c) * 9;
        unsigned short tmp[8];
#pragma unroll
        for (int k = 0; k < 8; ++k) tmp[k] = f2bf(src[k]);
        ((uint4*)w8)[(size_t)c * 256 + e] = *(const uint4*)tmp;
        w9[(size_t)c * 256 + e] = f2bf(src[8]);
        return;
    }

    if (blk < 704) {
        // 32x32 tiled transpose of head_w (z=0) / fuse_w (z=1..6)
        __shared__ float tile[32][33];
        int q = blk - 256;
        int z = q >> 6;
        int rem = q & 63;
        int bx = (rem & 7) * 32, by = (rem >> 3) * 32;
        const float* in = (z == 0) ? head_w : fuse_w + (size_t)(z - 1) * 65536;
        float* out = (z == 0) ? head_wT : fuse_wT + (size_t)(z - 1) * 65536;
        int tx = t & 31, ty = t >> 5;
#pragma unroll
        for (int i = 0; i < 32; i += 8)
            tile[ty + i][tx] = in[(size_t)(by + ty + i) * 256 + bx + tx];
        __syncthreads();
#pragma unroll
        for (int i = 0; i < 32; i += 8)
            out[(size_t)(bx + ty + i) * 256 + by + tx] = tile[tx][ty + i];
        return;
    }

    // ROI align: roiT[n][p][c], p = i*3 + j
    {
        int q = blk - 704;
        int n = q / 9, p = q % 9;
        int i = p / 3, j = p % 3;
        int c = t;

        int lvl = level_idx[n];
        int b = batch_idx[n];
        const float sizes[5]  = {128.f, 64.f, 32.f, 16.f, 8.f};
        const float invstr[5] = {1.f/8.f, 1.f/16.f, 1.f/32.f, 1.f/64.f, 1.f/128.f};
        float scale = invstr[lvl];
        float hv = sizes[lvl];

        float x1 = boxes[n*4+0] * scale, y1 = boxes[n*4+1] * scale;
        float x2 = boxes[n*4+2] * scale, y2 = boxes[n*4+3] * scale;
        float rw = fmaxf(x2 - x1, 1.f), rh = fmaxf(y2 - y1, 1.f);
        float x = x1 + (((float)j + 0.5f) / 3.f) * rw;
        float y = y1 + (((float)i + 0.5f) / 3.f) * rh;

        bool valid = (y > -1.f) && (y < hv) && (x > -1.f) && (x < hv);
        float yc = fminf(fmaxf(y, 0.f), hv - 1.f);
        float xc = fminf(fmaxf(x, 0.f), hv - 1.f);
        int y0 = (int)floorf(yc), x0 = (int)floorf(xc);
        int hi = (int)(hv - 1.f);
        int y1i = min(y0 + 1, hi), x1i = min(x0 + 1, hi);
        float ly = yc - (float)y0, lx = xc - (float)x0;

        const float* base = fm + (((size_t)lvl * 2 + b) * 256 + c) * (128 * 128);
        float v00 = base[y0 * 128 + x0];
        float v01 = base[y0 * 128 + x1i];
        float v10 = base[y1i * 128 + x0];
        float v11 = base[y1i * 128 + x1i];
        float v = (1.f - ly) * (1.f - lx) * v00 + (1.f - ly) * lx * v01 +
                  ly * (1.f - lx) * v10 + ly * lx * v11;
        roiT[((size_t)n * 9 + p) * 256 + c] = valid ? v : 0.f;
    }
}

// ---------------- conv3x3 + GN + ReLU + pool, then last-block head epilogue ------
// Block = (n, e-quarter): 512 blocks x 512 threads (2 blocks/CU).
// conv thread: e_loc = t&63, ch = t>>6 (8 c-slices of 32 channels, in pairs).
// GN group = e/32: ch==0 wave lane==e_loc, groups in 32-lane halves.
// Epilogue: the block whose atomicAdd(counter[n]) returns 3 computes head+fuse for n.
__global__ __launch_bounds__(512, 2) void conv_gn_pool_head(
    const float* __restrict__ roiT,
    const unsigned short* __restrict__ w8, const unsigned short* __restrict__ w9,
    const float* __restrict__ gn_scale, const float* __restrict__ gn_bias,
    const float* __restrict__ boxes,
    const float* __restrict__ head_wT, const float* __restrict__ head_b,
    const float* __restrict__ spat_w, const float* __restrict__ spat_b,
    const float* __restrict__ sym_emb,
    const float* __restrict__ fuse_wT, const float* __restrict__ fuse_b,
    const int* __restrict__ sym_ids,
    float* __restrict__ pooled, int* __restrict__ counter,
    float* __restrict__ out) {
    __shared__ float lds_roi[256 * 12];   // [c][p], stride 12
    __shared__ float red[4 * 64 * 9];
    __shared__ float epi[1024];           // pl[256] | part[512] | fin[256]
    __shared__ int do_epi;

    int n  = blockIdx.x >> 2;
    int eq = blockIdx.x & 3;
    int t = threadIdx.x;
    int e_loc = t & 63;
    int ch = t >> 6;
    int e = eq * 64 + e_loc;

    // stage roiT[n] (2304 f32) via float4
    const float4* rsrc4 = (const float4*)(roiT + (size_t)n * 2304);
    for (int v4 = t; v4 < 576; v4 += 512) {
        float4 rv = rsrc4[v4];
        int p = v4 / 64, c4 = (v4 & 63) * 4;
        lds_roi[(c4 + 0) * 12 + p] = rv.x;
        lds_roi[(c4 + 1) * 12 + p] = rv.y;
        lds_roi[(c4 + 2) * 12 + p] = rv.z;
        lds_roi[(c4 + 3) * 12 + p] = rv.w;
    }
    __syncthreads();

    float accx[9], accy[9];   // channel-pair accumulators (v_pk_fma_f32 SLP)
#pragma unroll
    for (int p = 0; p < 9; ++p) { accx[p] = 0.f; accy[p] = 0.f; }

    int c0 = ch * 32;
    for (int c = c0; c < c0 + 32; c += 2) {
        float ra[9], rb[9];
#pragma unroll
        for (int jj = 0; jj < 9; ++jj) {
            ra[jj] = lds_roi[c * 12 + jj];
            rb[jj] = lds_roi[(c + 1) * 12 + jj];
        }
        uint4 wa4 = ((const uint4*)w8)[(size_t)c * 256 + e];
        uint4 wb4 = ((const uint4*)w8)[(size_t)(c + 1) * 256 + e];
        float wa[9], wb[9];
        wa[0] = bf_lo(wa4.x); wa[1] = bf_hi(wa4.x);
        wa[2] = bf_lo(wa4.y); wa[3] = bf_hi(wa4.y);
        wa[4] = bf_lo(wa4.z); wa[5] = bf_hi(wa4.z);
        wa[6] = bf_lo(wa4.w); wa[7] = bf_hi(wa4.w);
        wa[8] = bf_lo((unsigned)w9[(size_t)c * 256 + e]);
        wb[0] = bf_lo(wb4.x); wb[1] = bf_hi(wb4.x);
        wb[2] = bf_lo(wb4.y); wb[3] = bf_hi(wb4.y);
        wb[4] = bf_lo(wb4.z); wb[5] = bf_hi(wb4.z);
        wb[6] = bf_lo(wb4.w); wb[7] = bf_hi(wb4.w);
        wb[8] = bf_lo((unsigned)w9[(size_t)(c + 1) * 256 + e]);
#pragma unroll
        for (int ky = 0; ky < 3; ++ky) {
#pragma unroll
            for (int kx = 0; kx < 3; ++kx) {
                float wav = wa[ky * 3 + kx], wbv = wb[ky * 3 + kx];
#pragma unroll
                for (int oy = 0; oy < 3; ++oy) {
                    int iy = oy + ky - 1;
                    if (iy < 0 || iy > 2) continue;
#pragma unroll
                    for (int ox = 0; ox < 3; ++ox) {
                        int ix = ox + kx - 1;
                        if (ix < 0 || ix > 2) continue;
                        int o = oy * 3 + ox, in = iy * 3 + ix;
                        accx[o] = fmaf(wav, ra[in], accx[o]);
                        accy[o] = fmaf(wbv, rb[in], accy[o]);
                    }
                }
            }
        }
    }

    float acc[9];
#pragma unroll
    for (int p = 0; p < 9; ++p) acc[p] = accx[p] + accy[p];

    // tree-reduce 8 c-slices into ch==0
    if (ch >= 4) {
#pragma unroll
        for (int p = 0; p < 9; ++p) red[((ch - 4) * 64 + e_loc) * 9 + p] = acc[p];
    }
    __syncthreads();
    if (ch < 4) {
#pragma unroll
        for (int p = 0; p < 9; ++p) acc[p] += red[(ch * 64 + e_loc) * 9 + p];
    }
    __syncthreads();
    if (ch >= 2 && ch < 4) {
#pragma unroll
        for (int p = 0; p < 9; ++p) red[((ch - 2) * 64 + e_loc) * 9 + p] = acc[p];
    }
    __syncthreads();
    if (ch < 2) {
#pragma unroll
        for (int p = 0; p < 9; ++p) acc[p] += red[(ch * 64 + e_loc) * 9 + p];
    }
    __syncthreads();
    if (ch == 1) {
#pragma unroll
        for (int p = 0; p < 9; ++p) red[e_loc * 9 + p] = acc[p];
    }
    __syncthreads();
    if (ch == 0) {
#pragma unroll
        for (int p = 0; p < 9; ++p) acc[p] += red[e_loc * 9 + p];

        float s = 0.f, sq = 0.f;
#pragma unroll
        for (int p = 0; p < 9; ++p) { s += acc[p]; sq += acc[p] * acc[p]; }
#pragma unroll
        for (int m = 16; m >= 1; m >>= 1) {
            s  += __shfl_xor(s, m, 64);
            sq += __shfl_xor(sq, m, 64);
        }
        float mean = s * (1.f / 288.f);
        float var = sq * (1.f / 288.f) - mean * mean;
        float rinv = rsqrtf(var + 1e-5f);
        float gs = gn_scale[e], gb = gn_bias[e];
        float ps = 0.f;
#pragma unroll
        for (int p = 0; p < 9; ++p) {
            float v = (acc[p] - mean) * rinv * gs + gb;
            ps += fmaxf(v, 0.f);
        }
        pooled[(size_t)n * 256 + e] = ps * (1.f / 9.f);
    }

    // ---- last-block-per-sample election ----
    __syncthreads();                     // drains vmcnt: pooled stores complete
    if (t == 0) {
        __threadfence();                 // device-scope release (L2 writeback)
        int old = atomicAdd(&counter[n], 1);
        do_epi = (old == 3);
    }
    __syncthreads();
    if (!do_epi) return;
    __threadfence();                     // device-scope acquire (invalidate stale)

    // ---- head GEMM + spat + sym_emb + fuse matvec for sample n ----
    float* pl   = epi;                   // [256]
    float* part = epi + 256;             // [512]
    float* fin  = epi + 768;             // [256] (aliases part tail? no: 768..1024)
    int e2 = t & 255;
    int kh = t >> 8;                     // 0/1
    int sid = sym_ids[n];

    if (t < 256) pl[t] = pooled[(size_t)n * 256 + t];
    __syncthreads();

    {
        float a = 0.f;
        const float* w = head_wT + (size_t)(kh * 128) * 256 + e2;
        const float* p = pl + kh * 128;
#pragma unroll 8
        for (int k = 0; k < 128; ++k) a = fmaf(p[k], w[k * 256], a);
        part[t] = a;
    }
    __syncthreads();
    if (t < 256) {
        float ho = fmaxf(part[t] + part[t + 256] + head_b[t], 0.f);
        float4 sw = ((const float4*)spat_w)[t];
        float b0 = boxes[n*4+0], b1 = boxes[n*4+1], b2 = boxes[n*4+2], b3 = boxes[n*4+3];
        float sp = fmaxf(spat_b[t] + b0*sw.x + b1*sw.y + b2*sw.z + b3*sw.w, 0.f);
        fin[t] = ho + sp + sym_emb[sid * 256 + t];
    }
    __syncthreads();
    {
        float o = 0.f;
        const float* w = fuse_wT + (size_t)sid * 65536 + (size_t)(kh * 128) * 256 + e2;
        const float* p = fin + kh * 128;
#pragma unroll 8
        for (int k = 0; k < 128; ++k) o = fmaf(p[k], w[k * 256], o);
        part[t] = o;
    }
    __syncthreads();
    if (t < 256)
        out[(size_t)n * 256 + t] = fmaxf(part[t] + part[t + 256] + fuse_b[sid * 256 + t], 0.f);
}

extern "C" void kernel_launch(void* const* d_in, const int* in_sizes, int n_in,
                              void* d_out, int out_size, void* d_ws, size_t ws_size,
                              hipStream_t stream) {
    const float* fm      = (const float*)d_in[0];
    const float* boxes   = (const float*)d_in[1];
    const float* conv_w  = (const float*)d_in[2];
    const float* gn_s    = (const float*)d_in[3];
    const float* gn_b    = (const float*)d_in[4];
    const float* head_w  = (const float*)d_in[5];
    const float* head_b  = (const float*)d_in[6];
    const float* spat_w  = (const float*)d_in[7];
    const float* spat_b  = (const float*)d_in[8];
    const float* sym_emb = (const float*)d_in[9];
    const float* fuse_w  = (const float*)d_in[10];
    const float* fuse_b  = (const float*)d_in[11];
    const int* batch_idx = (const int*)d_in[12];
    const int* level_idx = (const int*)d_in[13];
    const int* sym_ids   = (const int*)d_in[14];
    float* outp = (float*)d_out;

    char* ws = (char*)d_ws;
    unsigned short* w8 = (unsigned short*)ws;             // [256c][256e][8] bf16: 1,048,576 B
    unsigned short* w9 = (unsigned short*)(ws + 1048576); // [256c][256e] bf16  :   131,072 B
    float* head_wT = (float*)(ws + 1179648);              // [256][256]         :   262,144 B
    float* fuse_wT = (float*)(ws + 1441792);              // [6][256][256]      : 1,572,864 B
    float* roiT    = (float*)(ws + 3014656);              // [128][9][256]      : 1,179,648 B
    float* pooled  = (float*)(ws + 4194304);              // [128][256]         :   131,072 B
    int*   counter = (int*)(ws + 4325376);                // [128]              :       512 B

    prep_k<<<1856, 256, 0, stream>>>(conv_w, head_w, fuse_w, fm, boxes,
                                     batch_idx, level_idx,
                                     w8, w9, head_wT, fuse_wT, roiT, counter);
    conv_gn_pool_head<<<512, 512, 0, stream>>>(roiT, w8, w9, gn_s, gn_b,
                                               boxes, head_wT, head_b, spat_w, spat_b,
                                               sym_emb, fuse_wT, fuse_b, sym_ids,
                                               pooled, counter, outp);
}

// Round 7
// 264.058 us; speedup vs baseline: 1.1554x; 1.1554x over previous
//
#include <hip/hip_runtime.h>
#include <hip/hip_bf16.h>

// Pipeline: roi_align -> conv3x3(C=256->E=256 on 3x3 spatial, pad 1) -> GroupNorm(8)
//           -> ReLU -> spatial mean -> head GEMM -> +spat +sym_emb -> per-sid fuse matvec.
// Sizes: B=2, C=E=256, S=3, L=5, N=128, HMAX=128.
// 3 launches: prep(w_prep + t7 + roi[1 block/sample]) -> conv_gn_pool -> head_fuse.
// R6: reverted R5's last-block epilogue (device-scope __threadfence in 512 blocks
// cost +45us — L2 drain per block). Stream-ordered kernel boundary is cheaper.

__device__ __forceinline__ float bf_lo(unsigned u) { return __uint_as_float(u << 16); }
__device__ __forceinline__ float bf_hi(unsigned u) { return __uint_as_float(u & 0xffff0000u); }
__device__ __forceinline__ unsigned short f2bf(float f) {
    __hip_bfloat16 h = __float2bfloat16(f);
    return *(unsigned short*)&h;
}

// ---------------- fused prep kernel ----------------
// grid.x: [0,256)   w_prep (block=c, thread=e)
//         [256,704) t7     (448 transpose tiles: head_w + 6x fuse_w)
//         [704,832) roi    (block=n, thread=c, all 9 grid points -> 36 gathers/lane)
__global__ __launch_bounds__(256) void prep_k(
    const float* __restrict__ conv_w,
    const float* __restrict__ head_w, const float* __restrict__ fuse_w,
    const float* __restrict__ fm, const float* __restrict__ boxes,
    const int* __restrict__ batch_idx, const int* __restrict__ level_idx,
    unsigned short* __restrict__ w8, unsigned short* __restrict__ w9,
    float* __restrict__ head_wT, float* __restrict__ fuse_wT,
    float* __restrict__ roiT) {
    int blk = blockIdx.x;
    int t = threadIdx.x;

    if (blk < 256) {
        // conv weight repack: [e][c][9] f32 -> w8[c][e][8] + w9[c][e] bf16
        int c = blk, e = t;
        const float* src = conv_w + ((size_t)e * 256 + c) * 9;
        unsigned short tmp[8];
#pragma unroll
        for (int k = 0; k < 8; ++k) tmp[k] = f2bf(src[k]);
        ((uint4*)w8)[(size_t)c * 256 + e] = *(const uint4*)tmp;
        w9[(size_t)c * 256 + e] = f2bf(src[8]);
        return;
    }

    if (blk < 704) {
        // 32x32 tiled transpose of head_w (z=0) / fuse_w (z=1..6)
        __shared__ float tile[32][33];
        int q = blk - 256;
        int z = q >> 6;
        int rem = q & 63;
        int bx = (rem & 7) * 32, by = (rem >> 3) * 32;
        const float* in = (z == 0) ? head_w : fuse_w + (size_t)(z - 1) * 65536;
        float* out = (z == 0) ? head_wT : fuse_wT + (size_t)(z - 1) * 65536;
        int tx = t & 31, ty = t >> 5;
#pragma unroll
        for (int i = 0; i < 32; i += 8)
            tile[ty + i][tx] = in[(size_t)(by + ty + i) * 256 + bx + tx];
        __syncthreads();
#pragma unroll
        for (int i = 0; i < 32; i += 8)
            out[(size_t)(bx + ty + i) * 256 + by + tx] = tile[tx][ty + i];
        return;
    }

    // ROI align, one block per sample: roiT[n][p][c], p = i*3 + j
    {
        int n = blk - 704;
        int c = t;

        int lvl = level_idx[n];
        int b = batch_idx[n];
        const float sizes[5]  = {128.f, 64.f, 32.f, 16.f, 8.f};
        const float invstr[5] = {1.f/8.f, 1.f/16.f, 1.f/32.f, 1.f/64.f, 1.f/128.f};
        float scale = invstr[lvl];
        float hv = sizes[lvl];

        float x1 = boxes[n*4+0] * scale, y1 = boxes[n*4+1] * scale;
        float x2 = boxes[n*4+2] * scale, y2 = boxes[n*4+3] * scale;
        float rw = fmaxf(x2 - x1, 1.f), rh = fmaxf(y2 - y1, 1.f);
        const float* base = fm + (((size_t)lvl * 2 + b) * 256 + c) * (128 * 128);
        float* dst = roiT + (size_t)n * 2304 + c;
        int hi = (int)(hv - 1.f);

#pragma unroll
        for (int p = 0; p < 9; ++p) {
            int i = p / 3, j = p % 3;
            float x = x1 + (((float)j + 0.5f) / 3.f) * rw;
            float y = y1 + (((float)i + 0.5f) / 3.f) * rh;
            bool valid = (y > -1.f) && (y < hv) && (x > -1.f) && (x < hv);
            float yc = fminf(fmaxf(y, 0.f), hv - 1.f);
            float xc = fminf(fmaxf(x, 0.f), hv - 1.f);
            int y0 = (int)floorf(yc), x0 = (int)floorf(xc);
            int y1i = min(y0 + 1, hi), x1i = min(x0 + 1, hi);
            float ly = yc - (float)y0, lx = xc - (float)x0;
            float v00 = base[y0 * 128 + x0];
            float v01 = base[y0 * 128 + x1i];
            float v10 = base[y1i * 128 + x0];
            float v11 = base[y1i * 128 + x1i];
            float v = (1.f - ly) * (1.f - lx) * v00 + (1.f - ly) * lx * v01 +
                      ly * (1.f - lx) * v10 + ly * lx * v11;
            dst[p * 256] = valid ? v : 0.f;
        }
    }
}

// ---------------- conv3x3 + GroupNorm + ReLU + spatial-mean ----------------
// Block = (n, e-quarter): 512 blocks x 512 threads (2 blocks/CU).
// thread: e_loc = t&63, ch = t>>6 (8 c-slices of 32 channels, processed in pairs).
// GN group = e/32: ch==0 wave lane==e_loc, groups in 32-lane halves.
// LDS roi layout [p][c]: staging is dense ds_write_b128; conv reads are wave-broadcast.
__global__ __launch_bounds__(512, 2) void conv_gn_pool(
    const float* __restrict__ roiT,
    const unsigned short* __restrict__ w8, const unsigned short* __restrict__ w9,
    const float* __restrict__ gn_scale, const float* __restrict__ gn_bias,
    float* __restrict__ pooled) {
    __shared__ float lds_roi[2304];       // [p][c]
    __shared__ float red[4 * 64 * 9];

    int n  = blockIdx.x >> 2;
    int eq = blockIdx.x & 3;
    int t = threadIdx.x;
    int e_loc = t & 63;
    int ch = t >> 6;
    int e = eq * 64 + e_loc;

    // stage roiT[n] (2304 f32) via float4, identity layout
    const float4* rsrc4 = (const float4*)(roiT + (size_t)n * 2304);
    float4* ldst4 = (float4*)lds_roi;
    for (int v4 = t; v4 < 576; v4 += 512) ldst4[v4] = rsrc4[v4];
    __syncthreads();

    float accx[9], accy[9];   // channel-pair accumulators (v_pk_fma_f32 SLP)
#pragma unroll
    for (int p = 0; p < 9; ++p) { accx[p] = 0.f; accy[p] = 0.f; }

    int c0 = ch * 32;
    for (int c = c0; c < c0 + 32; c += 2) {
        float ra[9], rb[9];
#pragma unroll
        for (int jj = 0; jj < 9; ++jj) {
            ra[jj] = lds_roi[jj * 256 + c];
            rb[jj] = lds_roi[jj * 256 + c + 1];
        }
        uint4 wa4 = ((const uint4*)w8)[(size_t)c * 256 + e];
        uint4 wb4 = ((const uint4*)w8)[(size_t)(c + 1) * 256 + e];
        float wa[9], wb[9];
        wa[0] = bf_lo(wa4.x); wa[1] = bf_hi(wa4.x);
        wa[2] = bf_lo(wa4.y); wa[3] = bf_hi(wa4.y);
        wa[4] = bf_lo(wa4.z); wa[5] = bf_hi(wa4.z);
        wa[6] = bf_lo(wa4.w); wa[7] = bf_hi(wa4.w);
        wa[8] = bf_lo((unsigned)w9[(size_t)c * 256 + e]);
        wb[0] = bf_lo(wb4.x); wb[1] = bf_hi(wb4.x);
        wb[2] = bf_lo(wb4.y); wb[3] = bf_hi(wb4.y);
        wb[4] = bf_lo(wb4.z); wb[5] = bf_hi(wb4.z);
        wb[6] = bf_lo(wb4.w); wb[7] = bf_hi(wb4.w);
        wb[8] = bf_lo((unsigned)w9[(size_t)(c + 1) * 256 + e]);
#pragma unroll
        for (int ky = 0; ky < 3; ++ky) {
#pragma unroll
            for (int kx = 0; kx < 3; ++kx) {
                float wav = wa[ky * 3 + kx], wbv = wb[ky * 3 + kx];
#pragma unroll
                for (int oy = 0; oy < 3; ++oy) {
                    int iy = oy + ky - 1;
                    if (iy < 0 || iy > 2) continue;
#pragma unroll
                    for (int ox = 0; ox < 3; ++ox) {
                        int ix = ox + kx - 1;
                        if (ix < 0 || ix > 2) continue;
                        int o = oy * 3 + ox, in = iy * 3 + ix;
                        accx[o] = fmaf(wav, ra[in], accx[o]);
                        accy[o] = fmaf(wbv, rb[in], accy[o]);
                    }
                }
            }
        }
    }

    float acc[9];
#pragma unroll
    for (int p = 0; p < 9; ++p) acc[p] = accx[p] + accy[p];

    // tree-reduce 8 c-slices into ch==0
    if (ch >= 4) {
#pragma unroll
        for (int p = 0; p < 9; ++p) red[((ch - 4) * 64 + e_loc) * 9 + p] = acc[p];
    }
    __syncthreads();
    if (ch < 4) {
#pragma unroll
        for (int p = 0; p < 9; ++p) acc[p] += red[(ch * 64 + e_loc) * 9 + p];
    }
    __syncthreads();
    if (ch >= 2 && ch < 4) {
#pragma unroll
        for (int p = 0; p < 9; ++p) red[((ch - 2) * 64 + e_loc) * 9 + p] = acc[p];
    }
    __syncthreads();
    if (ch < 2) {
#pragma unroll
        for (int p = 0; p < 9; ++p) acc[p] += red[(ch * 64 + e_loc) * 9 + p];
    }
    __syncthreads();
    if (ch == 1) {
#pragma unroll
        for (int p = 0; p < 9; ++p) red[e_loc * 9 + p] = acc[p];
    }
    __syncthreads();
    if (ch == 0) {
#pragma unroll
        for (int p = 0; p < 9; ++p) acc[p] += red[e_loc * 9 + p];

        float s = 0.f, sq = 0.f;
#pragma unroll
        for (int p = 0; p < 9; ++p) { s += acc[p]; sq += acc[p] * acc[p]; }
#pragma unroll
        for (int m = 16; m >= 1; m >>= 1) {
            s  += __shfl_xor(s, m, 64);
            sq += __shfl_xor(sq, m, 64);
        }
        float mean = s * (1.f / 288.f);
        float var = sq * (1.f / 288.f) - mean * mean;
        float rinv = rsqrtf(var + 1e-5f);
        float gs = gn_scale[e], gb = gn_bias[e];
        float ps = 0.f;
#pragma unroll
        for (int p = 0; p < 9; ++p) {
            float v = (acc[p] - mean) * rinv * gs + gb;
            ps += fmaxf(v, 0.f);
        }
        pooled[(size_t)n * 256 + e] = ps * (1.f / 9.f);
    }
}

// ---------------- head GEMM + spat + sym_emb + fuse matvec (k-split x2) ----------------
// block = n (128 blocks x 512 threads). t = kh*256 + e; transposed weights so
// lane-consecutive threads read consecutive addresses (coalesced).
__global__ __launch_bounds__(512) void head_fuse(
    const float* __restrict__ pooled, const float* __restrict__ boxes,
    const float* __restrict__ head_wT, const float* __restrict__ head_b,
    const float* __restrict__ spat_w, const float* __restrict__ spat_b,
    const float* __restrict__ sym_emb,
    const float* __restrict__ fuse_wT, const float* __restrict__ fuse_b,
    const int* __restrict__ sym_ids, float* __restrict__ out) {
    __shared__ float pl[256];
    __shared__ float part[512];
    __shared__ float fin[256];
    int n = blockIdx.x;
    int t = threadIdx.x;
    int e = t & 255;
    int kh = t >> 8;                      // 0/1
    int sid = sym_ids[n];

    if (t < 256) pl[t] = pooled[(size_t)n * 256 + t];
    __syncthreads();

    {
        float acc = 0.f;
        const float* w = head_wT + (size_t)(kh * 128) * 256 + e;
        const float* p = pl + kh * 128;
#pragma unroll 8
        for (int k = 0; k < 128; ++k) acc = fmaf(p[k], w[k * 256], acc);
        part[t] = acc;
    }
    __syncthreads();
    if (t < 256) {
        float ho = fmaxf(part[t] + part[t + 256] + head_b[t], 0.f);
        float4 sw = ((const float4*)spat_w)[t];
        float b0 = boxes[n*4+0], b1 = boxes[n*4+1], b2 = boxes[n*4+2], b3 = boxes[n*4+3];
        float sp = fmaxf(spat_b[t] + b0*sw.x + b1*sw.y + b2*sw.z + b3*sw.w, 0.f);
        fin[t] = ho + sp + sym_emb[sid * 256 + t];
    }
    __syncthreads();
    {
        float o = 0.f;
        const float* w = fuse_wT + (size_t)sid * 65536 + (size_t)(kh * 128) * 256 + e;
        const float* p = fin + kh * 128;
#pragma unroll 8
        for (int k = 0; k < 128; ++k) o = fmaf(p[k], w[k * 256], o);
        part[t] = o;
    }
    __syncthreads();
    if (t < 256)
        out[(size_t)n * 256 + t] = fmaxf(part[t] + part[t + 256] + fuse_b[sid * 256 + t], 0.f);
}

extern "C" void kernel_launch(void* const* d_in, const int* in_sizes, int n_in,
                              void* d_out, int out_size, void* d_ws, size_t ws_size,
                              hipStream_t stream) {
    const float* fm      = (const float*)d_in[0];
    const float* boxes   = (const float*)d_in[1];
    const float* conv_w  = (const float*)d_in[2];
    const float* gn_s    = (const float*)d_in[3];
    const float* gn_b    = (const float*)d_in[4];
    const float* head_w  = (const float*)d_in[5];
    const float* head_b  = (const float*)d_in[6];
    const float* spat_w  = (const float*)d_in[7];
    const float* spat_b  = (const float*)d_in[8];
    const float* sym_emb = (const float*)d_in[9];
    const float* fuse_w  = (const float*)d_in[10];
    const float* fuse_b  = (const float*)d_in[11];
    const int* batch_idx = (const int*)d_in[12];
    const int* level_idx = (const int*)d_in[13];
    const int* sym_ids   = (const int*)d_in[14];
    float* outp = (float*)d_out;

    char* ws = (char*)d_ws;
    unsigned short* w8 = (unsigned short*)ws;             // [256c][256e][8] bf16: 1,048,576 B
    unsigned short* w9 = (unsigned short*)(ws + 1048576); // [256c][256e] bf16  :   131,072 B
    float* head_wT = (float*)(ws + 1179648);              // [256][256]         :   262,144 B
    float* fuse_wT = (float*)(ws + 1441792);              // [6][256][256]      : 1,572,864 B
    float* roiT    = (float*)(ws + 3014656);              // [128][9][256]      : 1,179,648 B
    float* pooled  = (float*)(ws + 4194304);              // [128][256]         :   131,072 B

    prep_k<<<832, 256, 0, stream>>>(conv_w, head_w, fuse_w, fm, boxes,
                                    batch_idx, level_idx,
                                    w8, w9, head_wT, fuse_wT, roiT);
    conv_gn_pool<<<512, 512, 0, stream>>>(roiT, w8, w9, gn_s, gn_b, pooled);
    head_fuse<<<128, 512, 0, stream>>>(pooled, boxes, head_wT, head_b, spat_w, spat_b,
                                       sym_emb, fuse_wT, fuse_b, sym_ids, outp);
}

// Round 8
// 261.502 us; speedup vs baseline: 1.1667x; 1.0098x over previous
//
#include <hip/hip_runtime.h>
#include <hip/hip_bf16.h>

// Pipeline: roi_align -> conv3x3(C=256->E=256 on 3x3 spatial, pad 1) -> GroupNorm(8)
//           -> ReLU -> spatial mean -> head GEMM -> +spat +sym_emb -> per-sid fuse matvec.
// Sizes: B=2, C=E=256, S=3, L=5, N=128, HMAX=128.
// 3 launches: prep(w_prep + t7 + roi[(n,p)-block]) -> conv_gn_pool -> head_fuse.
// R7: ROI back to 1152 (n,p)-blocks (R6's 128-block roi serialized gathers, +4us);
// keep R6's dense [p][c] LDS staging. R5 lesson: no device-scope fences in hot blocks.

__device__ __forceinline__ float bf_lo(unsigned u) { return __uint_as_float(u << 16); }
__device__ __forceinline__ float bf_hi(unsigned u) { return __uint_as_float(u & 0xffff0000u); }
__device__ __forceinline__ unsigned short f2bf(float f) {
    __hip_bfloat16 h = __float2bfloat16(f);
    return *(unsigned short*)&h;
}

// ---------------- fused prep kernel ----------------
// grid.x: [0,256)    w_prep (block=c, thread=e)
//         [256,704)  t7     (448 transpose tiles: head_w + 6x fuse_w)
//         [704,1856) roi    (block=(n,p), thread=c)
__global__ __launch_bounds__(256) void prep_k(
    const float* __restrict__ conv_w,
    const float* __restrict__ head_w, const float* __restrict__ fuse_w,
    const float* __restrict__ fm, const float* __restrict__ boxes,
    const int* __restrict__ batch_idx, const int* __restrict__ level_idx,
    unsigned short* __restrict__ w8, unsigned short* __restrict__ w9,
    float* __restrict__ head_wT, float* __restrict__ fuse_wT,
    float* __restrict__ roiT) {
    int blk = blockIdx.x;
    int t = threadIdx.x;

    if (blk < 256) {
        // conv weight repack: [e][c][9] f32 -> w8[c][e][8] + w9[c][e] bf16
        int c = blk, e = t;
        const float* src = conv_w + ((size_t)e * 256 + c) * 9;
        unsigned short tmp[8];
#pragma unroll
        for (int k = 0; k < 8; ++k) tmp[k] = f2bf(src[k]);
        ((uint4*)w8)[(size_t)c * 256 + e] = *(const uint4*)tmp;
        w9[(size_t)c * 256 + e] = f2bf(src[8]);
        return;
    }

    if (blk < 704) {
        // 32x32 tiled transpose of head_w (z=0) / fuse_w (z=1..6)
        __shared__ float tile[32][33];
        int q = blk - 256;
        int z = q >> 6;
        int rem = q & 63;
        int bx = (rem & 7) * 32, by = (rem >> 3) * 32;
        const float* in = (z == 0) ? head_w : fuse_w + (size_t)(z - 1) * 65536;
        float* out = (z == 0) ? head_wT : fuse_wT + (size_t)(z - 1) * 65536;
        int tx = t & 31, ty = t >> 5;
#pragma unroll
        for (int i = 0; i < 32; i += 8)
            tile[ty + i][tx] = in[(size_t)(by + ty + i) * 256 + bx + tx];
        __syncthreads();
#pragma unroll
        for (int i = 0; i < 32; i += 8)
            out[(size_t)(bx + ty + i) * 256 + by + tx] = tile[tx][ty + i];
        return;
    }

    // ROI align: roiT[n][p][c], p = i*3 + j
    {
        int q = blk - 704;
        int n = q / 9, p = q % 9;
        int i = p / 3, j = p % 3;
        int c = t;

        int lvl = level_idx[n];
        int b = batch_idx[n];
        const float sizes[5]  = {128.f, 64.f, 32.f, 16.f, 8.f};
        const float invstr[5] = {1.f/8.f, 1.f/16.f, 1.f/32.f, 1.f/64.f, 1.f/128.f};
        float scale = invstr[lvl];
        float hv = sizes[lvl];

        float x1 = boxes[n*4+0] * scale, y1 = boxes[n*4+1] * scale;
        float x2 = boxes[n*4+2] * scale, y2 = boxes[n*4+3] * scale;
        float rw = fmaxf(x2 - x1, 1.f), rh = fmaxf(y2 - y1, 1.f);
        float x = x1 + (((float)j + 0.5f) / 3.f) * rw;
        float y = y1 + (((float)i + 0.5f) / 3.f) * rh;

        bool valid = (y > -1.f) && (y < hv) && (x > -1.f) && (x < hv);
        float yc = fminf(fmaxf(y, 0.f), hv - 1.f);
        float xc = fminf(fmaxf(x, 0.f), hv - 1.f);
        int y0 = (int)floorf(yc), x0 = (int)floorf(xc);
        int hi = (int)(hv - 1.f);
        int y1i = min(y0 + 1, hi), x1i = min(x0 + 1, hi);
        float ly = yc - (float)y0, lx = xc - (float)x0;

        const float* base = fm + (((size_t)lvl * 2 + b) * 256 + c) * (128 * 128);
        float v00 = base[y0 * 128 + x0];
        float v01 = base[y0 * 128 + x1i];
        float v10 = base[y1i * 128 + x0];
        float v11 = base[y1i * 128 + x1i];
        float v = (1.f - ly) * (1.f - lx) * v00 + (1.f - ly) * lx * v01 +
                  ly * (1.f - lx) * v10 + ly * lx * v11;
        roiT[((size_t)n * 9 + p) * 256 + c] = valid ? v : 0.f;
    }
}

// ---------------- conv3x3 + GroupNorm + ReLU + spatial-mean ----------------
// Block = (n, e-quarter): 512 blocks x 512 threads (2 blocks/CU).
// thread: e_loc = t&63, ch = t>>6 (8 c-slices of 32 channels, processed in pairs).
// GN group = e/32: ch==0 wave lane==e_loc, groups in 32-lane halves.
// LDS roi layout [p][c]: dense float4 staging; conv reads are wave-broadcast.
__global__ __launch_bounds__(512, 2) void conv_gn_pool(
    const float* __restrict__ roiT,
    const unsigned short* __restrict__ w8, const unsigned short* __restrict__ w9,
    const float* __restrict__ gn_scale, const float* __restrict__ gn_bias,
    float* __restrict__ pooled) {
    __shared__ float lds_roi[2304];       // [p][c]
    __shared__ float red[4 * 64 * 9];

    int n  = blockIdx.x >> 2;
    int eq = blockIdx.x & 3;
    int t = threadIdx.x;
    int e_loc = t & 63;
    int ch = t >> 6;
    int e = eq * 64 + e_loc;

    // stage roiT[n] (2304 f32) via float4, identity layout
    const float4* rsrc4 = (const float4*)(roiT + (size_t)n * 2304);
    float4* ldst4 = (float4*)lds_roi;
    for (int v4 = t; v4 < 576; v4 += 512) ldst4[v4] = rsrc4[v4];
    __syncthreads();

    float accx[9], accy[9];   // channel-pair accumulators (v_pk_fma_f32 SLP)
#pragma unroll
    for (int p = 0; p < 9; ++p) { accx[p] = 0.f; accy[p] = 0.f; }

    int c0 = ch * 32;
    for (int c = c0; c < c0 + 32; c += 2) {
        float ra[9], rb[9];
#pragma unroll
        for (int jj = 0; jj < 9; ++jj) {
            ra[jj] = lds_roi[jj * 256 + c];
            rb[jj] = lds_roi[jj * 256 + c + 1];
        }
        uint4 wa4 = ((const uint4*)w8)[(size_t)c * 256 + e];
        uint4 wb4 = ((const uint4*)w8)[(size_t)(c + 1) * 256 + e];
        float wa[9], wb[9];
        wa[0] = bf_lo(wa4.x); wa[1] = bf_hi(wa4.x);
        wa[2] = bf_lo(wa4.y); wa[3] = bf_hi(wa4.y);
        wa[4] = bf_lo(wa4.z); wa[5] = bf_hi(wa4.z);
        wa[6] = bf_lo(wa4.w); wa[7] = bf_hi(wa4.w);
        wa[8] = bf_lo((unsigned)w9[(size_t)c * 256 + e]);
        wb[0] = bf_lo(wb4.x); wb[1] = bf_hi(wb4.x);
        wb[2] = bf_lo(wb4.y); wb[3] = bf_hi(wb4.y);
        wb[4] = bf_lo(wb4.z); wb[5] = bf_hi(wb4.z);
        wb[6] = bf_lo(wb4.w); wb[7] = bf_hi(wb4.w);
        wb[8] = bf_lo((unsigned)w9[(size_t)(c + 1) * 256 + e]);
#pragma unroll
        for (int ky = 0; ky < 3; ++ky) {
#pragma unroll
            for (int kx = 0; kx < 3; ++kx) {
                float wav = wa[ky * 3 + kx], wbv = wb[ky * 3 + kx];
#pragma unroll
                for (int oy = 0; oy < 3; ++oy) {
                    int iy = oy + ky - 1;
                    if (iy < 0 || iy > 2) continue;
#pragma unroll
                    for (int ox = 0; ox < 3; ++ox) {
                        int ix = ox + kx - 1;
                        if (ix < 0 || ix > 2) continue;
                        int o = oy * 3 + ox, in = iy * 3 + ix;
                        accx[o] = fmaf(wav, ra[in], accx[o]);
                        accy[o] = fmaf(wbv, rb[in], accy[o]);
                    }
                }
            }
        }
    }

    float acc[9];
#pragma unroll
    for (int p = 0; p < 9; ++p) acc[p] = accx[p] + accy[p];

    // tree-reduce 8 c-slices into ch==0
    if (ch >= 4) {
#pragma unroll
        for (int p = 0; p < 9; ++p) red[((ch - 4) * 64 + e_loc) * 9 + p] = acc[p];
    }
    __syncthreads();
    if (ch < 4) {
#pragma unroll
        for (int p = 0; p < 9; ++p) acc[p] += red[(ch * 64 + e_loc) * 9 + p];
    }
    __syncthreads();
    if (ch >= 2 && ch < 4) {
#pragma unroll
        for (int p = 0; p < 9; ++p) red[((ch - 2) * 64 + e_loc) * 9 + p] = acc[p];
    }
    __syncthreads();
    if (ch < 2) {
#pragma unroll
        for (int p = 0; p < 9; ++p) acc[p] += red[(ch * 64 + e_loc) * 9 + p];
    }
    __syncthreads();
    if (ch == 1) {
#pragma unroll
        for (int p = 0; p < 9; ++p) red[e_loc * 9 + p] = acc[p];
    }
    __syncthreads();
    if (ch == 0) {
#pragma unroll
        for (int p = 0; p < 9; ++p) acc[p] += red[e_loc * 9 + p];

        float s = 0.f, sq = 0.f;
#pragma unroll
        for (int p = 0; p < 9; ++p) { s += acc[p]; sq += acc[p] * acc[p]; }
#pragma unroll
        for (int m = 16; m >= 1; m >>= 1) {
            s  += __shfl_xor(s, m, 64);
            sq += __shfl_xor(sq, m, 64);
        }
        float mean = s * (1.f / 288.f);
        float var = sq * (1.f / 288.f) - mean * mean;
        float rinv = rsqrtf(var + 1e-5f);
        float gs = gn_scale[e], gb = gn_bias[e];
        float ps = 0.f;
#pragma unroll
        for (int p = 0; p < 9; ++p) {
            float v = (acc[p] - mean) * rinv * gs + gb;
            ps += fmaxf(v, 0.f);
        }
        pooled[(size_t)n * 256 + e] = ps * (1.f / 9.f);
    }
}

// ---------------- head GEMM + spat + sym_emb + fuse matvec (k-split x2) ----------------
// block = n (128 blocks x 512 threads). t = kh*256 + e; transposed weights so
// lane-consecutive threads read consecutive addresses (coalesced).
__global__ __launch_bounds__(512) void head_fuse(
    const float* __restrict__ pooled, const float* __restrict__ boxes,
    const float* __restrict__ head_wT, const float* __restrict__ head_b,
    const float* __restrict__ spat_w, const float* __restrict__ spat_b,
    const float* __restrict__ sym_emb,
    const float* __restrict__ fuse_wT, const float* __restrict__ fuse_b,
    const int* __restrict__ sym_ids, float* __restrict__ out) {
    __shared__ float pl[256];
    __shared__ float part[512];
    __shared__ float fin[256];
    int n = blockIdx.x;
    int t = threadIdx.x;
    int e = t & 255;
    int kh = t >> 8;                      // 0/1
    int sid = sym_ids[n];

    if (t < 256) pl[t] = pooled[(size_t)n * 256 + t];
    __syncthreads();

    {
        float acc = 0.f;
        const float* w = head_wT + (size_t)(kh * 128) * 256 + e;
        const float* p = pl + kh * 128;
#pragma unroll 8
        for (int k = 0; k < 128; ++k) acc = fmaf(p[k], w[k * 256], acc);
        part[t] = acc;
    }
    __syncthreads();
    if (t < 256) {
        float ho = fmaxf(part[t] + part[t + 256] + head_b[t], 0.f);
        float4 sw = ((const float4*)spat_w)[t];
        float b0 = boxes[n*4+0], b1 = boxes[n*4+1], b2 = boxes[n*4+2], b3 = boxes[n*4+3];
        float sp = fmaxf(spat_b[t] + b0*sw.x + b1*sw.y + b2*sw.z + b3*sw.w, 0.f);
        fin[t] = ho + sp + sym_emb[sid * 256 + t];
    }
    __syncthreads();
    {
        float o = 0.f;
        const float* w = fuse_wT + (size_t)sid * 65536 + (size_t)(kh * 128) * 256 + e;
        const float* p = fin + kh * 128;
#pragma unroll 8
        for (int k = 0; k < 128; ++k) o = fmaf(p[k], w[k * 256], o);
        part[t] = o;
    }
    __syncthreads();
    if (t < 256)
        out[(size_t)n * 256 + t] = fmaxf(part[t] + part[t + 256] + fuse_b[sid * 256 + t], 0.f);
}

extern "C" void kernel_launch(void* const* d_in, const int* in_sizes, int n_in,
                              void* d_out, int out_size, void* d_ws, size_t ws_size,
                              hipStream_t stream) {
    const float* fm      = (const float*)d_in[0];
    const float* boxes   = (const float*)d_in[1];
    const float* conv_w  = (const float*)d_in[2];
    const float* gn_s    = (const float*)d_in[3];
    const float* gn_b    = (const float*)d_in[4];
    const float* head_w  = (const float*)d_in[5];
    const float* head_b  = (const float*)d_in[6];
    const float* spat_w  = (const float*)d_in[7];
    const float* spat_b  = (const float*)d_in[8];
    const float* sym_emb = (const float*)d_in[9];
    const float* fuse_w  = (const float*)d_in[10];
    const float* fuse_b  = (const float*)d_in[11];
    const int* batch_idx = (const int*)d_in[12];
    const int* level_idx = (const int*)d_in[13];
    const int* sym_ids   = (const int*)d_in[14];
    float* outp = (float*)d_out;

    char* ws = (char*)d_ws;
    unsigned short* w8 = (unsigned short*)ws;             // [256c][256e][8] bf16: 1,048,576 B
    unsigned short* w9 = (unsigned short*)(ws + 1048576); // [256c][256e] bf16  :   131,072 B
    float* head_wT = (float*)(ws + 1179648);              // [256][256]         :   262,144 B
    float* fuse_wT = (float*)(ws + 1441792);              // [6][256][256]      : 1,572,864 B
    float* roiT    = (float*)(ws + 3014656);              // [128][9][256]      : 1,179,648 B
    float* pooled  = (float*)(ws + 4194304);              // [128][256]         :   131,072 B

    prep_k<<<1856, 256, 0, stream>>>(conv_w, head_w, fuse_w, fm, boxes,
                                     batch_idx, level_idx,
                                     w8, w9, head_wT, fuse_wT, roiT);
    conv_gn_pool<<<512, 512, 0, stream>>>(roiT, w8, w9, gn_s, gn_b, pooled);
    head_fuse<<<128, 512, 0, stream>>>(pooled, boxes, head_wT, head_b, spat_w, spat_b,
                                       sym_emb, fuse_wT, fuse_b, sym_ids, outp);
}

// Round 9
// 257.883 us; speedup vs baseline: 1.1831x; 1.0140x over previous
//
#include <hip/hip_runtime.h>
#include <hip/hip_bf16.h>

// Pipeline: roi_align -> conv3x3(C=256->E=256 on 3x3 spatial, pad 1) -> GroupNorm(8)
//           -> ReLU -> spatial mean -> head GEMM -> +spat +sym_emb -> per-sid fuse matvec.
// Sizes: B=2, C=E=256, S=3, L=5, N=128, HMAX=128.
// 3 launches: prep(w_prep + t7 + roi[(n,p)-block]) -> conv_gn_pool -> head_fuse.
// R8: conv restructure — (a) roi values are wave-uniform -> scalar (SMEM) loads
// straight from global, LDS staging dropped; (b) sample-pair blocks (256 x 512)
// halve conv weight L2 traffic (147 -> 74 MB). R5 lesson: no device fences.

__device__ __forceinline__ float bf_lo(unsigned u) { return __uint_as_float(u << 16); }
__device__ __forceinline__ float bf_hi(unsigned u) { return __uint_as_float(u & 0xffff0000u); }
__device__ __forceinline__ unsigned short f2bf(float f) {
    __hip_bfloat16 h = __float2bfloat16(f);
    return *(unsigned short*)&h;
}

// ---------------- fused prep kernel ----------------
// grid.x: [0,256)    w_prep (block=c, thread=e)
//         [256,704)  t7     (448 transpose tiles: head_w + 6x fuse_w)
//         [704,1856) roi    (block=(n,p), thread=c)
__global__ __launch_bounds__(256) void prep_k(
    const float* __restrict__ conv_w,
    const float* __restrict__ head_w, const float* __restrict__ fuse_w,
    const float* __restrict__ fm, const float* __restrict__ boxes,
    const int* __restrict__ batch_idx, const int* __restrict__ level_idx,
    unsigned short* __restrict__ w8, unsigned short* __restrict__ w9,
    float* __restrict__ head_wT, float* __restrict__ fuse_wT,
    float* __restrict__ roiT) {
    int blk = blockIdx.x;
    int t = threadIdx.x;

    if (blk < 256) {
        // conv weight repack: [e][c][9] f32 -> w8[c][e][8] + w9[c][e] bf16
        int c = blk, e = t;
        const float* src = conv_w + ((size_t)e * 256 + c) * 9;
        unsigned short tmp[8];
#pragma unroll
        for (int k = 0; k < 8; ++k) tmp[k] = f2bf(src[k]);
        ((uint4*)w8)[(size_t)c * 256 + e] = *(const uint4*)tmp;
        w9[(size_t)c * 256 + e] = f2bf(src[8]);
        return;
    }

    if (blk < 704) {
        // 32x32 tiled transpose of head_w (z=0) / fuse_w (z=1..6)
        __shared__ float tile[32][33];
        int q = blk - 256;
        int z = q >> 6;
        int rem = q & 63;
        int bx = (rem & 7) * 32, by = (rem >> 3) * 32;
        const float* in = (z == 0) ? head_w : fuse_w + (size_t)(z - 1) * 65536;
        float* out = (z == 0) ? head_wT : fuse_wT + (size_t)(z - 1) * 65536;
        int tx = t & 31, ty = t >> 5;
#pragma unroll
        for (int i = 0; i < 32; i += 8)
            tile[ty + i][tx] = in[(size_t)(by + ty + i) * 256 + bx + tx];
        __syncthreads();
#pragma unroll
        for (int i = 0; i < 32; i += 8)
            out[(size_t)(bx + ty + i) * 256 + by + tx] = tile[tx][ty + i];
        return;
    }

    // ROI align: roiT[n][p][c], p = i*3 + j
    {
        int q = blk - 704;
        int n = q / 9, p = q % 9;
        int i = p / 3, j = p % 3;
        int c = t;

        int lvl = level_idx[n];
        int b = batch_idx[n];
        const float sizes[5]  = {128.f, 64.f, 32.f, 16.f, 8.f};
        const float invstr[5] = {1.f/8.f, 1.f/16.f, 1.f/32.f, 1.f/64.f, 1.f/128.f};
        float scale = invstr[lvl];
        float hv = sizes[lvl];

        float x1 = boxes[n*4+0] * scale, y1 = boxes[n*4+1] * scale;
        float x2 = boxes[n*4+2] * scale, y2 = boxes[n*4+3] * scale;
        float rw = fmaxf(x2 - x1, 1.f), rh = fmaxf(y2 - y1, 1.f);
        float x = x1 + (((float)j + 0.5f) / 3.f) * rw;
        float y = y1 + (((float)i + 0.5f) / 3.f) * rh;

        bool valid = (y > -1.f) && (y < hv) && (x > -1.f) && (x < hv);
        float yc = fminf(fmaxf(y, 0.f), hv - 1.f);
        float xc = fminf(fmaxf(x, 0.f), hv - 1.f);
        int y0 = (int)floorf(yc), x0 = (int)floorf(xc);
        int hi = (int)(hv - 1.f);
        int y1i = min(y0 + 1, hi), x1i = min(x0 + 1, hi);
        float ly = yc - (float)y0, lx = xc - (float)x0;

        const float* base = fm + (((size_t)lvl * 2 + b) * 256 + c) * (128 * 128);
        float v00 = base[y0 * 128 + x0];
        float v01 = base[y0 * 128 + x1i];
        float v10 = base[y1i * 128 + x0];
        float v11 = base[y1i * 128 + x1i];
        float v = (1.f - ly) * (1.f - lx) * v00 + (1.f - ly) * lx * v01 +
                  ly * (1.f - lx) * v10 + ly * lx * v11;
        roiT[((size_t)n * 9 + p) * 256 + c] = valid ? v : 0.f;
    }
}

// ---------------- conv3x3 + GroupNorm + ReLU + spatial-mean ----------------
// Block = (n-pair, e-quarter): 256 blocks x 512 threads.
// thread: e_loc = t&63, ch = t>>6 (8 c-slices of 32 channels); each thread does
// BOTH samples of the pair (weights loaded once, used twice).
// roi values are wave-uniform (ch uniform per wave) -> scalar loads from global,
// no LDS staging. GN group = e/32: 32-lane halves; ch==0 wave -> sample n0,
// ch==1 wave -> sample n1.
__global__ __launch_bounds__(512, 2) void conv_gn_pool(
    const float* __restrict__ roiT,
    const unsigned short* __restrict__ w8, const unsigned short* __restrict__ w9,
    const float* __restrict__ gn_scale, const float* __restrict__ gn_bias,
    float* __restrict__ pooled) {
    __shared__ float redA[4 * 64 * 9];
    __shared__ float redB[4 * 64 * 9];

    int np = blockIdx.x >> 2;             // 0..63 sample pair
    int eq = blockIdx.x & 3;
    int n0 = np * 2, n1 = n0 + 1;
    int t = threadIdx.x;
    int e_loc = t & 63;
    int ch = __builtin_amdgcn_readfirstlane(t >> 6);   // wave-uniform 0..7
    int e = eq * 64 + e_loc;

    const float* r0 = roiT + (size_t)n0 * 2304;   // [p][c]
    const float* r1 = roiT + (size_t)n1 * 2304;

    float acc0[9], acc1[9];
#pragma unroll
    for (int p = 0; p < 9; ++p) { acc0[p] = 0.f; acc1[p] = 0.f; }

    int c0 = ch * 32;
#pragma unroll 4
    for (int c = c0; c < c0 + 32; ++c) {
        float ra[9], rb[9];
#pragma unroll
        for (int jj = 0; jj < 9; ++jj) {
            ra[jj] = r0[jj * 256 + c];    // uniform address -> s_load
            rb[jj] = r1[jj * 256 + c];
        }
        uint4 wa4 = ((const uint4*)w8)[(size_t)c * 256 + e];
        float wv[9];
        wv[0] = bf_lo(wa4.x); wv[1] = bf_hi(wa4.x);
        wv[2] = bf_lo(wa4.y); wv[3] = bf_hi(wa4.y);
        wv[4] = bf_lo(wa4.z); wv[5] = bf_hi(wa4.z);
        wv[6] = bf_lo(wa4.w); wv[7] = bf_hi(wa4.w);
        wv[8] = bf_lo((unsigned)w9[(size_t)c * 256 + e]);
#pragma unroll
        for (int ky = 0; ky < 3; ++ky) {
#pragma unroll
            for (int kx = 0; kx < 3; ++kx) {
                float w = wv[ky * 3 + kx];
#pragma unroll
                for (int oy = 0; oy < 3; ++oy) {
                    int iy = oy + ky - 1;
                    if (iy < 0 || iy > 2) continue;
#pragma unroll
                    for (int ox = 0; ox < 3; ++ox) {
                        int ix = ox + kx - 1;
                        if (ix < 0 || ix > 2) continue;
                        int o = oy * 3 + ox, in = iy * 3 + ix;
                        acc0[o] = fmaf(w, ra[in], acc0[o]);
                        acc1[o] = fmaf(w, rb[in], acc1[o]);
                    }
                }
            }
        }
    }

    // tree-reduce 8 c-slices into ch==0 (sample0) / ch==1 (sample1)
    if (ch >= 4) {
#pragma unroll
        for (int p = 0; p < 9; ++p) {
            redA[((ch - 4) * 64 + e_loc) * 9 + p] = acc0[p];
            redB[((ch - 4) * 64 + e_loc) * 9 + p] = acc1[p];
        }
    }
    __syncthreads();
    if (ch < 4) {
#pragma unroll
        for (int p = 0; p < 9; ++p) {
            acc0[p] += redA[(ch * 64 + e_loc) * 9 + p];
            acc1[p] += redB[(ch * 64 + e_loc) * 9 + p];
        }
    }
    __syncthreads();
    if (ch >= 2 && ch < 4) {
#pragma unroll
        for (int p = 0; p < 9; ++p) {
            redA[((ch - 2) * 64 + e_loc) * 9 + p] = acc0[p];
            redB[((ch - 2) * 64 + e_loc) * 9 + p] = acc1[p];
        }
    }
    __syncthreads();
    if (ch < 2) {
#pragma unroll
        for (int p = 0; p < 9; ++p) {
            acc0[p] += redA[(ch * 64 + e_loc) * 9 + p];
            acc1[p] += redB[(ch * 64 + e_loc) * 9 + p];
        }
    }
    __syncthreads();
    if (ch == 1) {
#pragma unroll
        for (int p = 0; p < 9; ++p) redA[e_loc * 9 + p] = acc0[p];
    }
    if (ch == 0) {
#pragma unroll
        for (int p = 0; p < 9; ++p) redB[e_loc * 9 + p] = acc1[p];
    }
    __syncthreads();

    if (ch < 2) {
        float acc[9];
        int n_out;
        if (ch == 0) {
            n_out = n0;
#pragma unroll
            for (int p = 0; p < 9; ++p) acc[p] = acc0[p] + redA[e_loc * 9 + p];
        } else {
            n_out = n1;
#pragma unroll
            for (int p = 0; p < 9; ++p) acc[p] = acc1[p] + redB[e_loc * 9 + p];
        }

        float s = 0.f, sq = 0.f;
#pragma unroll
        for (int p = 0; p < 9; ++p) { s += acc[p]; sq += acc[p] * acc[p]; }
#pragma unroll
        for (int m = 16; m >= 1; m >>= 1) {
            s  += __shfl_xor(s, m, 64);
            sq += __shfl_xor(sq, m, 64);
        }
        float mean = s * (1.f / 288.f);
        float var = sq * (1.f / 288.f) - mean * mean;
        float rinv = rsqrtf(var + 1e-5f);
        float gs = gn_scale[e], gb = gn_bias[e];
        float ps = 0.f;
#pragma unroll
        for (int p = 0; p < 9; ++p) {
            float v = (acc[p] - mean) * rinv * gs + gb;
            ps += fmaxf(v, 0.f);
        }
        pooled[(size_t)n_out * 256 + e] = ps * (1.f / 9.f);
    }
}

// ---------------- head GEMM + spat + sym_emb + fuse matvec (k-split x2) ----------------
// block = n (128 blocks x 512 threads). t = kh*256 + e; transposed weights so
// lane-consecutive threads read consecutive addresses (coalesced).
__global__ __launch_bounds__(512) void head_fuse(
    const float* __restrict__ pooled, const float* __restrict__ boxes,
    const float* __restrict__ head_wT, const float* __restrict__ head_b,
    const float* __restrict__ spat_w, const float* __restrict__ spat_b,
    const float* __restrict__ sym_emb,
    const float* __restrict__ fuse_wT, const float* __restrict__ fuse_b,
    const int* __restrict__ sym_ids, float* __restrict__ out) {
    __shared__ float pl[256];
    __shared__ float part[512];
    __shared__ float fin[256];
    int n = blockIdx.x;
    int t = threadIdx.x;
    int e = t & 255;
    int kh = t >> 8;                      // 0/1
    int sid = sym_ids[n];

    if (t < 256) pl[t] = pooled[(size_t)n * 256 + t];
    __syncthreads();

    {
        float acc = 0.f;
        const float* w = head_wT + (size_t)(kh * 128) * 256 + e;
        const float* p = pl + kh * 128;
#pragma unroll 8
        for (int k = 0; k < 128; ++k) acc = fmaf(p[k], w[k * 256], acc);
        part[t] = acc;
    }
    __syncthreads();
    if (t < 256) {
        float ho = fmaxf(part[t] + part[t + 256] + head_b[t], 0.f);
        float4 sw = ((const float4*)spat_w)[t];
        float b0 = boxes[n*4+0], b1 = boxes[n*4+1], b2 = boxes[n*4+2], b3 = boxes[n*4+3];
        float sp = fmaxf(spat_b[t] + b0*sw.x + b1*sw.y + b2*sw.z + b3*sw.w, 0.f);
        fin[t] = ho + sp + sym_emb[sid * 256 + t];
    }
    __syncthreads();
    {
        float o = 0.f;
        const float* w = fuse_wT + (size_t)sid * 65536 + (size_t)(kh * 128) * 256 + e;
        const float* p = fin + kh * 128;
#pragma unroll 8
        for (int k = 0; k < 128; ++k) o = fmaf(p[k], w[k * 256], o);
        part[t] = o;
    }
    __syncthreads();
    if (t < 256)
        out[(size_t)n * 256 + t] = fmaxf(part[t] + part[t + 256] + fuse_b[sid * 256 + t], 0.f);
}

extern "C" void kernel_launch(void* const* d_in, const int* in_sizes, int n_in,
                              void* d_out, int out_size, void* d_ws, size_t ws_size,
                              hipStream_t stream) {
    const float* fm      = (const float*)d_in[0];
    const float* boxes   = (const float*)d_in[1];
    const float* conv_w  = (const float*)d_in[2];
    const float* gn_s    = (const float*)d_in[3];
    const float* gn_b    = (const float*)d_in[4];
    const float* head_w  = (const float*)d_in[5];
    const float* head_b  = (const float*)d_in[6];
    const float* spat_w  = (const float*)d_in[7];
    const float* spat_b  = (const float*)d_in[8];
    const float* sym_emb = (const float*)d_in[9];
    const float* fuse_w  = (const float*)d_in[10];
    const float* fuse_b  = (const float*)d_in[11];
    const int* batch_idx = (const int*)d_in[12];
    const int* level_idx = (const int*)d_in[13];
    const int* sym_ids   = (const int*)d_in[14];
    float* outp = (float*)d_out;

    char* ws = (char*)d_ws;
    unsigned short* w8 = (unsigned short*)ws;             // [256c][256e][8] bf16: 1,048,576 B
    unsigned short* w9 = (unsigned short*)(ws + 1048576); // [256c][256e] bf16  :   131,072 B
    float* head_wT = (float*)(ws + 1179648);              // [256][256]         :   262,144 B
    float* fuse_wT = (float*)(ws + 1441792);              // [6][256][256]      : 1,572,864 B
    float* roiT    = (float*)(ws + 3014656);              // [128][9][256]      : 1,179,648 B
    float* pooled  = (float*)(ws + 4194304);              // [128][256]         :   131,072 B

    prep_k<<<1856, 256, 0, stream>>>(conv_w, head_w, fuse_w, fm, boxes,
                                     batch_idx, level_idx,
                                     w8, w9, head_wT, fuse_wT, roiT);
    conv_gn_pool<<<256, 512, 0, stream>>>(roiT, w8, w9, gn_s, gn_b, pooled);
    head_fuse<<<128, 512, 0, stream>>>(pooled, boxes, head_wT, head_b, spat_w, spat_b,
                                       sym_emb, fuse_wT, fuse_b, sym_ids, outp);
}

// Round 10
// 253.540 us; speedup vs baseline: 1.2033x; 1.0171x over previous
//
#include <hip/hip_runtime.h>
#include <hip/hip_bf16.h>

// Pipeline: roi_align -> conv3x3(C=256->E=256 on 3x3 spatial, pad 1) -> GroupNorm(8)
//           -> ReLU -> spatial mean -> head GEMM -> +spat +sym_emb -> per-sid fuse matvec.
// Sizes: B=2, C=E=256, S=3, L=5, N=128, HMAX=128.
// 3 launches: prep -> conv_gn_pool -> head_fuse.
// R9: (a) conv uses float2 ext-vector accs over the R8 sample-pair -> v_pk_fma_f32;
//     (b) head/fuse weights stored bf16 by t7 (halves head_fuse L2 traffic).
// R5 lesson: no device-scope fences in hot blocks. R3 lesson: transposed weights
// (lane-consecutive = address-consecutive) for the matvecs.

typedef float v2f __attribute__((ext_vector_type(2)));

__device__ __forceinline__ float bf_lo(unsigned u) { return __uint_as_float(u << 16); }
__device__ __forceinline__ float bf_hi(unsigned u) { return __uint_as_float(u & 0xffff0000u); }
__device__ __forceinline__ unsigned short f2bf(float f) {
    __hip_bfloat16 h = __float2bfloat16(f);
    return *(unsigned short*)&h;
}

// ---------------- fused prep kernel ----------------
// grid.x: [0,256)    w_prep (block=c, thread=e)
//         [256,704)  t7     (448 transpose tiles: head_w + 6x fuse_w, f32 -> bf16)
//         [704,1856) roi    (block=(n,p), thread=c)
__global__ __launch_bounds__(256) void prep_k(
    const float* __restrict__ conv_w,
    const float* __restrict__ head_w, const float* __restrict__ fuse_w,
    const float* __restrict__ fm, const float* __restrict__ boxes,
    const int* __restrict__ batch_idx, const int* __restrict__ level_idx,
    unsigned short* __restrict__ w8, unsigned short* __restrict__ w9,
    unsigned short* __restrict__ head_wTb, unsigned short* __restrict__ fuse_wTb,
    float* __restrict__ roiT) {
    int blk = blockIdx.x;
    int t = threadIdx.x;

    if (blk < 256) {
        // conv weight repack: [e][c][9] f32 -> w8[c][e][8] + w9[c][e] bf16
        int c = blk, e = t;
        const float* src = conv_w + ((size_t)e * 256 + c) * 9;
        unsigned short tmp[8];
#pragma unroll
        for (int k = 0; k < 8; ++k) tmp[k] = f2bf(src[k]);
        ((uint4*)w8)[(size_t)c * 256 + e] = *(const uint4*)tmp;
        w9[(size_t)c * 256 + e] = f2bf(src[8]);
        return;
    }

    if (blk < 704) {
        // 32x32 tiled transpose of head_w (z=0) / fuse_w (z=1..6), output bf16
        __shared__ float tile[32][33];
        int q = blk - 256;
        int z = q >> 6;
        int rem = q & 63;
        int bx = (rem & 7) * 32, by = (rem >> 3) * 32;
        const float* in = (z == 0) ? head_w : fuse_w + (size_t)(z - 1) * 65536;
        unsigned short* out = (z == 0) ? head_wTb : fuse_wTb + (size_t)(z - 1) * 65536;
        int tx = t & 31, ty = t >> 5;
#pragma unroll
        for (int i = 0; i < 32; i += 8)
            tile[ty + i][tx] = in[(size_t)(by + ty + i) * 256 + bx + tx];
        __syncthreads();
#pragma unroll
        for (int i = 0; i < 32; i += 8)
            out[(size_t)(bx + ty + i) * 256 + by + tx] = f2bf(tile[tx][ty + i]);
        return;
    }

    // ROI align: roiT[n][p][c], p = i*3 + j
    {
        int q = blk - 704;
        int n = q / 9, p = q % 9;
        int i = p / 3, j = p % 3;
        int c = t;

        int lvl = level_idx[n];
        int b = batch_idx[n];
        const float sizes[5]  = {128.f, 64.f, 32.f, 16.f, 8.f};
        const float invstr[5] = {1.f/8.f, 1.f/16.f, 1.f/32.f, 1.f/64.f, 1.f/128.f};
        float scale = invstr[lvl];
        float hv = sizes[lvl];

        float x1 = boxes[n*4+0] * scale, y1 = boxes[n*4+1] * scale;
        float x2 = boxes[n*4+2] * scale, y2 = boxes[n*4+3] * scale;
        float rw = fmaxf(x2 - x1, 1.f), rh = fmaxf(y2 - y1, 1.f);
        float x = x1 + (((float)j + 0.5f) / 3.f) * rw;
        float y = y1 + (((float)i + 0.5f) / 3.f) * rh;

        bool valid = (y > -1.f) && (y < hv) && (x > -1.f) && (x < hv);
        float yc = fminf(fmaxf(y, 0.f), hv - 1.f);
        float xc = fminf(fmaxf(x, 0.f), hv - 1.f);
        int y0 = (int)floorf(yc), x0 = (int)floorf(xc);
        int hi = (int)(hv - 1.f);
        int y1i = min(y0 + 1, hi), x1i = min(x0 + 1, hi);
        float ly = yc - (float)y0, lx = xc - (float)x0;

        const float* base = fm + (((size_t)lvl * 2 + b) * 256 + c) * (128 * 128);
        float v00 = base[y0 * 128 + x0];
        float v01 = base[y0 * 128 + x1i];
        float v10 = base[y1i * 128 + x0];
        float v11 = base[y1i * 128 + x1i];
        float v = (1.f - ly) * (1.f - lx) * v00 + (1.f - ly) * lx * v01 +
                  ly * (1.f - lx) * v10 + ly * lx * v11;
        roiT[((size_t)n * 9 + p) * 256 + c] = valid ? v : 0.f;
    }
}

// ---------------- conv3x3 + GroupNorm + ReLU + spatial-mean ----------------
// Block = (n-pair, e-quarter): 256 blocks x 512 threads.
// thread: e_loc = t&63, ch = t>>6 (8 c-slices of 32 channels); each thread does
// BOTH samples of the pair as a float2 lane (.x = n0, .y = n1) -> v_pk_fma_f32.
// roi values are wave-uniform (ch uniform per wave) -> scalar loads from global.
// GN group = e/32: 32-lane halves; ch==0 wave -> sample n0, ch==1 -> n1.
__global__ __launch_bounds__(512, 2) void conv_gn_pool(
    const float* __restrict__ roiT,
    const unsigned short* __restrict__ w8, const unsigned short* __restrict__ w9,
    const float* __restrict__ gn_scale, const float* __restrict__ gn_bias,
    float* __restrict__ pooled) {
    __shared__ float redA[4 * 64 * 9];
    __shared__ float redB[4 * 64 * 9];

    int np = blockIdx.x >> 2;             // 0..63 sample pair
    int eq = blockIdx.x & 3;
    int n0 = np * 2, n1 = n0 + 1;
    int t = threadIdx.x;
    int e_loc = t & 63;
    int ch = __builtin_amdgcn_readfirstlane(t >> 6);   // wave-uniform 0..7
    int e = eq * 64 + e_loc;

    const float* r0 = roiT + (size_t)n0 * 2304;   // [p][c]
    const float* r1 = roiT + (size_t)n1 * 2304;

    v2f acc[9];
#pragma unroll
    for (int p = 0; p < 9; ++p) acc[p] = (v2f)(0.f);

    int c0 = ch * 32;
#pragma unroll 4
    for (int c = c0; c < c0 + 32; ++c) {
        v2f r[9];
#pragma unroll
        for (int jj = 0; jj < 9; ++jj) {
            r[jj].x = r0[jj * 256 + c];   // uniform address -> s_load
            r[jj].y = r1[jj * 256 + c];
        }
        uint4 wa4 = ((const uint4*)w8)[(size_t)c * 256 + e];
        float wv[9];
        wv[0] = bf_lo(wa4.x); wv[1] = bf_hi(wa4.x);
        wv[2] = bf_lo(wa4.y); wv[3] = bf_hi(wa4.y);
        wv[4] = bf_lo(wa4.z); wv[5] = bf_hi(wa4.z);
        wv[6] = bf_lo(wa4.w); wv[7] = bf_hi(wa4.w);
        wv[8] = bf_lo((unsigned)w9[(size_t)c * 256 + e]);
#pragma unroll
        for (int ky = 0; ky < 3; ++ky) {
#pragma unroll
            for (int kx = 0; kx < 3; ++kx) {
                v2f w2;
                w2.x = wv[ky * 3 + kx]; w2.y = wv[ky * 3 + kx];
#pragma unroll
                for (int oy = 0; oy < 3; ++oy) {
                    int iy = oy + ky - 1;
                    if (iy < 0 || iy > 2) continue;
#pragma unroll
                    for (int ox = 0; ox < 3; ++ox) {
                        int ix = ox + kx - 1;
                        if (ix < 0 || ix > 2) continue;
                        int o = oy * 3 + ox, in = iy * 3 + ix;
                        acc[o] = w2 * r[in] + acc[o];   // ffp-contract -> v_pk_fma_f32
                    }
                }
            }
        }
    }

    float acc0[9], acc1[9];
#pragma unroll
    for (int p = 0; p < 9; ++p) { acc0[p] = acc[p].x; acc1[p] = acc[p].y; }

    // tree-reduce 8 c-slices into ch==0 (sample0) / ch==1 (sample1)
    if (ch >= 4) {
#pragma unroll
        for (int p = 0; p < 9; ++p) {
            redA[((ch - 4) * 64 + e_loc) * 9 + p] = acc0[p];
            redB[((ch - 4) * 64 + e_loc) * 9 + p] = acc1[p];
        }
    }
    __syncthreads();
    if (ch < 4) {
#pragma unroll
        for (int p = 0; p < 9; ++p) {
            acc0[p] += redA[(ch * 64 + e_loc) * 9 + p];
            acc1[p] += redB[(ch * 64 + e_loc) * 9 + p];
        }
    }
    __syncthreads();
    if (ch >= 2 && ch < 4) {
#pragma unroll
        for (int p = 0; p < 9; ++p) {
            redA[((ch - 2) * 64 + e_loc) * 9 + p] = acc0[p];
            redB[((ch - 2) * 64 + e_loc) * 9 + p] = acc1[p];
        }
    }
    __syncthreads();
    if (ch < 2) {
#pragma unroll
        for (int p = 0; p < 9; ++p) {
            acc0[p] += redA[(ch * 64 + e_loc) * 9 + p];
            acc1[p] += redB[(ch * 64 + e_loc) * 9 + p];
        }
    }
    __syncthreads();
    if (ch == 1) {
#pragma unroll
        for (int p = 0; p < 9; ++p) redA[e_loc * 9 + p] = acc0[p];
    }
    if (ch == 0) {
#pragma unroll
        for (int p = 0; p < 9; ++p) redB[e_loc * 9 + p] = acc1[p];
    }
    __syncthreads();

    if (ch < 2) {
        float accf[9];
        int n_out;
        if (ch == 0) {
            n_out = n0;
#pragma unroll
            for (int p = 0; p < 9; ++p) accf[p] = acc0[p] + redA[e_loc * 9 + p];
        } else {
            n_out = n1;
#pragma unroll
            for (int p = 0; p < 9; ++p) accf[p] = acc1[p] + redB[e_loc * 9 + p];
        }

        float s = 0.f, sq = 0.f;
#pragma unroll
        for (int p = 0; p < 9; ++p) { s += accf[p]; sq += accf[p] * accf[p]; }
#pragma unroll
        for (int m = 16; m >= 1; m >>= 1) {
            s  += __shfl_xor(s, m, 64);
            sq += __shfl_xor(sq, m, 64);
        }
        float mean = s * (1.f / 288.f);
        float var = sq * (1.f / 288.f) - mean * mean;
        float rinv = rsqrtf(var + 1e-5f);
        float gs = gn_scale[e], gb = gn_bias[e];
        float ps = 0.f;
#pragma unroll
        for (int p = 0; p < 9; ++p) {
            float v = (accf[p] - mean) * rinv * gs + gb;
            ps += fmaxf(v, 0.f);
        }
        pooled[(size_t)n_out * 256 + e] = ps * (1.f / 9.f);
    }
}

// ---------------- head GEMM + spat + sym_emb + fuse matvec (k-split x2) ----------------
// block = n (128 blocks x 512 threads). t = kh*256 + e; transposed bf16 weights:
// lane-consecutive threads read consecutive ushorts (coalesced, half traffic).
__global__ __launch_bounds__(512) void head_fuse(
    const float* __restrict__ pooled, const float* __restrict__ boxes,
    const unsigned short* __restrict__ head_wTb, const float* __restrict__ head_b,
    const float* __restrict__ spat_w, const float* __restrict__ spat_b,
    const float* __restrict__ sym_emb,
    const unsigned short* __restrict__ fuse_wTb, const float* __restrict__ fuse_b,
    const int* __restrict__ sym_ids, float* __restrict__ out) {
    __shared__ float pl[256];
    __shared__ float part[512];
    __shared__ float fin[256];
    int n = blockIdx.x;
    int t = threadIdx.x;
    int e = t & 255;
    int kh = t >> 8;                      // 0/1
    int sid = sym_ids[n];

    if (t < 256) pl[t] = pooled[(size_t)n * 256 + t];
    __syncthreads();

    {
        float acc = 0.f;
        const unsigned short* w = head_wTb + (size_t)(kh * 128) * 256 + e;
        const float* p = pl + kh * 128;
#pragma unroll 8
        for (int k = 0; k < 128; ++k) acc = fmaf(p[k], bf_lo((unsigned)w[k * 256]), acc);
        part[t] = acc;
    }
    __syncthreads();
    if (t < 256) {
        float ho = fmaxf(part[t] + part[t + 256] + head_b[t], 0.f);
        float4 sw = ((const float4*)spat_w)[t];
        float b0 = boxes[n*4+0], b1 = boxes[n*4+1], b2 = boxes[n*4+2], b3 = boxes[n*4+3];
        float sp = fmaxf(spat_b[t] + b0*sw.x + b1*sw.y + b2*sw.z + b3*sw.w, 0.f);
        fin[t] = ho + sp + sym_emb[sid * 256 + t];
    }
    __syncthreads();
    {
        float o = 0.f;
        const unsigned short* w = fuse_wTb + (size_t)sid * 65536 + (size_t)(kh * 128) * 256 + e;
        const float* p = fin + kh * 128;
#pragma unroll 8
        for (int k = 0; k < 128; ++k) o = fmaf(p[k], bf_lo((unsigned)w[k * 256]), o);
        part[t] = o;
    }
    __syncthreads();
    if (t < 256)
        out[(size_t)n * 256 + t] = fmaxf(part[t] + part[t + 256] + fuse_b[sid * 256 + t], 0.f);
}

extern "C" void kernel_launch(void* const* d_in, const int* in_sizes, int n_in,
                              void* d_out, int out_size, void* d_ws, size_t ws_size,
                              hipStream_t stream) {
    const float* fm      = (const float*)d_in[0];
    const float* boxes   = (const float*)d_in[1];
    const float* conv_w  = (const float*)d_in[2];
    const float* gn_s    = (const float*)d_in[3];
    const float* gn_b    = (const float*)d_in[4];
    const float* head_w  = (const float*)d_in[5];
    const float* head_b  = (const float*)d_in[6];
    const float* spat_w  = (const float*)d_in[7];
    const float* spat_b  = (const float*)d_in[8];
    const float* sym_emb = (const float*)d_in[9];
    const float* fuse_w  = (const float*)d_in[10];
    const float* fuse_b  = (const float*)d_in[11];
    const int* batch_idx = (const int*)d_in[12];
    const int* level_idx = (const int*)d_in[13];
    const int* sym_ids   = (const int*)d_in[14];
    float* outp = (float*)d_out;

    char* ws = (char*)d_ws;
    unsigned short* w8       = (unsigned short*)ws;             // [256c][256e][8] bf16: 1,048,576 B
    unsigned short* w9       = (unsigned short*)(ws + 1048576); // [256c][256e] bf16  :   131,072 B
    unsigned short* head_wTb = (unsigned short*)(ws + 1179648); // [256][256] bf16    :   131,072 B
    unsigned short* fuse_wTb = (unsigned short*)(ws + 1310720); // [6][256][256] bf16 :   786,432 B
    float* roiT    = (float*)(ws + 2097152);                    // [128][9][256]      : 1,179,648 B
    float* pooled  = (float*)(ws + 3276800);                    // [128][256]         :   131,072 B

    prep_k<<<1856, 256, 0, stream>>>(conv_w, head_w, fuse_w, fm, boxes,
                                     batch_idx, level_idx,
                                     w8, w9, head_wTb, fuse_wTb, roiT);
    conv_gn_pool<<<256, 512, 0, stream>>>(roiT, w8, w9, gn_s, gn_b, pooled);
    head_fuse<<<128, 512, 0, stream>>>(pooled, boxes, head_wTb, head_b, spat_w, spat_b,
                                       sym_emb, fuse_wTb, fuse_b, sym_ids, outp);
}

// Round 11
// 250.581 us; speedup vs baseline: 1.2175x; 1.0118x over previous
//
#include <hip/hip_runtime.h>
#include <hip/hip_bf16.h>

// Pipeline: roi_align -> conv3x3(C=256->E=256 on 3x3 spatial, pad 1) -> GroupNorm(8)
//           -> ReLU -> spatial mean -> head GEMM -> +spat +sym_emb -> per-sid fuse matvec.
// Sizes: B=2, C=E=256, S=3, L=5, N=128, HMAX=128.
// 3 launches: prep -> conv_gn_pool -> head_fuse.
// R10: conv c-pairing (s_load_dwordx2 roi, half SMEM instrs) on top of R8/R9
// sample-pair + pk-FMA; head/fuse weights stored k-paired bf16 (uint per lane,
// half weight-load instrs). R5 lesson: no device fences. R3: transposed weights.

typedef float v2f __attribute__((ext_vector_type(2)));

__device__ __forceinline__ float bf_lo(unsigned u) { return __uint_as_float(u << 16); }
__device__ __forceinline__ float bf_hi(unsigned u) { return __uint_as_float(u & 0xffff0000u); }
__device__ __forceinline__ unsigned short f2bf(float f) {
    __hip_bfloat16 h = __float2bfloat16(f);
    return *(unsigned short*)&h;
}

// ---------------- fused prep kernel ----------------
// grid.x: [0,256)    w_prep (block=c, thread=e)
//         [256,704)  t7     (448 tiles: head_w + 6x fuse_w -> transposed k-paired bf16)
//         [704,1856) roi    (block=(n,p), thread=c)
__global__ __launch_bounds__(256) void prep_k(
    const float* __restrict__ conv_w,
    const float* __restrict__ head_w, const float* __restrict__ fuse_w,
    const float* __restrict__ fm, const float* __restrict__ boxes,
    const int* __restrict__ batch_idx, const int* __restrict__ level_idx,
    unsigned short* __restrict__ w8, unsigned short* __restrict__ w9,
    unsigned short* __restrict__ head_wTb, unsigned short* __restrict__ fuse_wTb,
    float* __restrict__ roiT) {
    int blk = blockIdx.x;
    int t = threadIdx.x;

    if (blk < 256) {
        // conv weight repack: [e][c][9] f32 -> w8[c][e][8] + w9[c][e] bf16
        int c = blk, e = t;
        const float* src = conv_w + ((size_t)e * 256 + c) * 9;
        unsigned short tmp[8];
#pragma unroll
        for (int k = 0; k < 8; ++k) tmp[k] = f2bf(src[k]);
        ((uint4*)w8)[(size_t)c * 256 + e] = *(const uint4*)tmp;
        w9[(size_t)c * 256 + e] = f2bf(src[8]);
        return;
    }

    if (blk < 704) {
        // 32x32 tiled transpose of head_w (z=0) / fuse_w (z=1..6).
        // Output layout: k-paired bf16 — ushort index ((k>>1)*256 + e)*2 + (k&1),
        // so one uint per lane holds taps (k, k+1) for its e.
        __shared__ float tile[32][33];
        int q = blk - 256;
        int z = q >> 6;
        int rem = q & 63;
        int bx = (rem & 7) * 32, by = (rem >> 3) * 32;
        const float* in = (z == 0) ? head_w : fuse_w + (size_t)(z - 1) * 65536;
        unsigned short* out = (z == 0) ? head_wTb : fuse_wTb + (size_t)(z - 1) * 65536;
        int tx = t & 31, ty = t >> 5;
#pragma unroll
        for (int i = 0; i < 32; i += 8)
            tile[ty + i][tx] = in[(size_t)(by + ty + i) * 256 + bx + tx];
        __syncthreads();
#pragma unroll
        for (int i = 0; i < 32; i += 8) {
            int k = bx + ty + i;          // transposed row (original col)
            int e = by + tx;
            out[(size_t)((k >> 1) * 256 + e) * 2 + (k & 1)] = f2bf(tile[tx][ty + i]);
        }
        return;
    }

    // ROI align: roiT[n][p][c], p = i*3 + j
    {
        int q = blk - 704;
        int n = q / 9, p = q % 9;
        int i = p / 3, j = p % 3;
        int c = t;

        int lvl = level_idx[n];
        int b = batch_idx[n];
        const float sizes[5]  = {128.f, 64.f, 32.f, 16.f, 8.f};
        const float invstr[5] = {1.f/8.f, 1.f/16.f, 1.f/32.f, 1.f/64.f, 1.f/128.f};
        float scale = invstr[lvl];
        float hv = sizes[lvl];

        float x1 = boxes[n*4+0] * scale, y1 = boxes[n*4+1] * scale;
        float x2 = boxes[n*4+2] * scale, y2 = boxes[n*4+3] * scale;
        float rw = fmaxf(x2 - x1, 1.f), rh = fmaxf(y2 - y1, 1.f);
        float x = x1 + (((float)j + 0.5f) / 3.f) * rw;
        float y = y1 + (((float)i + 0.5f) / 3.f) * rh;

        bool valid = (y > -1.f) && (y < hv) && (x > -1.f) && (x < hv);
        float yc = fminf(fmaxf(y, 0.f), hv - 1.f);
        float xc = fminf(fmaxf(x, 0.f), hv - 1.f);
        int y0 = (int)floorf(yc), x0 = (int)floorf(xc);
        int hi = (int)(hv - 1.f);
        int y1i = min(y0 + 1, hi), x1i = min(x0 + 1, hi);
        float ly = yc - (float)y0, lx = xc - (float)x0;

        const float* base = fm + (((size_t)lvl * 2 + b) * 256 + c) * (128 * 128);
        float v00 = base[y0 * 128 + x0];
        float v01 = base[y0 * 128 + x1i];
        float v10 = base[y1i * 128 + x0];
        float v11 = base[y1i * 128 + x1i];
        float v = (1.f - ly) * (1.f - lx) * v00 + (1.f - ly) * lx * v01 +
                  ly * (1.f - lx) * v10 + ly * lx * v11;
        roiT[((size_t)n * 9 + p) * 256 + c] = valid ? v : 0.f;
    }
}

// ---------------- conv3x3 + GroupNorm + ReLU + spatial-mean ----------------
// Block = (n-pair, e-quarter): 256 blocks x 512 threads.
// thread: e_loc = t&63, ch = t>>6 (8 c-slices of 32 channels, c in pairs).
// Sample pair packed in v2f lanes (.x = n0, .y = n1) -> v_pk_fma_f32; roi values
// wave-uniform -> s_load_dwordx2 over adjacent c. GN group = e/32: 32-lane halves.
__global__ __launch_bounds__(512, 2) void conv_gn_pool(
    const float* __restrict__ roiT,
    const unsigned short* __restrict__ w8, const unsigned short* __restrict__ w9,
    const float* __restrict__ gn_scale, const float* __restrict__ gn_bias,
    float* __restrict__ pooled) {
    __shared__ float redA[4 * 64 * 9];
    __shared__ float redB[4 * 64 * 9];

    int np = blockIdx.x >> 2;             // 0..63 sample pair
    int eq = blockIdx.x & 3;
    int n0 = np * 2, n1 = n0 + 1;
    int t = threadIdx.x;
    int e_loc = t & 63;
    int ch = __builtin_amdgcn_readfirstlane(t >> 6);   // wave-uniform 0..7
    int e = eq * 64 + e_loc;

    const float* r0 = roiT + (size_t)n0 * 2304;   // [p][c]
    const float* r1 = roiT + (size_t)n1 * 2304;

    v2f acc[9];
#pragma unroll
    for (int p = 0; p < 9; ++p) acc[p] = (v2f)(0.f);

    int c0 = ch * 32;
#pragma unroll 2
    for (int c = c0; c < c0 + 32; c += 2) {
        // wave-uniform float2 roi loads (adjacent c, 8B-aligned) -> s_load_dwordx2
        v2f q0[9], q1[9];                 // q0: sample0 (c, c+1), q1: sample1
#pragma unroll
        for (int jj = 0; jj < 9; ++jj) {
            q0[jj] = *(const v2f*)(r0 + jj * 256 + c);
            q1[jj] = *(const v2f*)(r1 + jj * 256 + c);
        }
        // sample-packed uniform pairs per c
        v2f rc0[9], rc1[9];
#pragma unroll
        for (int jj = 0; jj < 9; ++jj) {
            rc0[jj].x = q0[jj].x; rc0[jj].y = q1[jj].x;   // channel c
            rc1[jj].x = q0[jj].y; rc1[jj].y = q1[jj].y;   // channel c+1
        }
#pragma unroll
        for (int cc = 0; cc < 2; ++cc) {
            const v2f* r = cc ? rc1 : rc0;
            int cw = c + cc;
            uint4 wa4 = ((const uint4*)w8)[(size_t)cw * 256 + e];
            float wv[9];
            wv[0] = bf_lo(wa4.x); wv[1] = bf_hi(wa4.x);
            wv[2] = bf_lo(wa4.y); wv[3] = bf_hi(wa4.y);
            wv[4] = bf_lo(wa4.z); wv[5] = bf_hi(wa4.z);
            wv[6] = bf_lo(wa4.w); wv[7] = bf_hi(wa4.w);
            wv[8] = bf_lo((unsigned)w9[(size_t)cw * 256 + e]);
#pragma unroll
            for (int ky = 0; ky < 3; ++ky) {
#pragma unroll
                for (int kx = 0; kx < 3; ++kx) {
                    v2f w2;
                    w2.x = wv[ky * 3 + kx]; w2.y = wv[ky * 3 + kx];
#pragma unroll
                    for (int oy = 0; oy < 3; ++oy) {
                        int iy = oy + ky - 1;
                        if (iy < 0 || iy > 2) continue;
#pragma unroll
                        for (int ox = 0; ox < 3; ++ox) {
                            int ix = ox + kx - 1;
                            if (ix < 0 || ix > 2) continue;
                            int o = oy * 3 + ox, in = iy * 3 + ix;
                            acc[o] = w2 * r[in] + acc[o];   // -> v_pk_fma_f32
                        }
                    }
                }
            }
        }
    }

    float acc0[9], acc1[9];
#pragma unroll
    for (int p = 0; p < 9; ++p) { acc0[p] = acc[p].x; acc1[p] = acc[p].y; }

    // tree-reduce 8 c-slices into ch==0 (sample0) / ch==1 (sample1)
    if (ch >= 4) {
#pragma unroll
        for (int p = 0; p < 9; ++p) {
            redA[((ch - 4) * 64 + e_loc) * 9 + p] = acc0[p];
            redB[((ch - 4) * 64 + e_loc) * 9 + p] = acc1[p];
        }
    }
    __syncthreads();
    if (ch < 4) {
#pragma unroll
        for (int p = 0; p < 9; ++p) {
            acc0[p] += redA[(ch * 64 + e_loc) * 9 + p];
            acc1[p] += redB[(ch * 64 + e_loc) * 9 + p];
        }
    }
    __syncthreads();
    if (ch >= 2 && ch < 4) {
#pragma unroll
        for (int p = 0; p < 9; ++p) {
            redA[((ch - 2) * 64 + e_loc) * 9 + p] = acc0[p];
            redB[((ch - 2) * 64 + e_loc) * 9 + p] = acc1[p];
        }
    }
    __syncthreads();
    if (ch < 2) {
#pragma unroll
        for (int p = 0; p < 9; ++p) {
            acc0[p] += redA[(ch * 64 + e_loc) * 9 + p];
            acc1[p] += redB[(ch * 64 + e_loc) * 9 + p];
        }
    }
    __syncthreads();
    if (ch == 1) {
#pragma unroll
        for (int p = 0; p < 9; ++p) redA[e_loc * 9 + p] = acc0[p];
    }
    if (ch == 0) {
#pragma unroll
        for (int p = 0; p < 9; ++p) redB[e_loc * 9 + p] = acc1[p];
    }
    __syncthreads();

    if (ch < 2) {
        float accf[9];
        int n_out;
        if (ch == 0) {
            n_out = n0;
#pragma unroll
            for (int p = 0; p < 9; ++p) accf[p] = acc0[p] + redA[e_loc * 9 + p];
        } else {
            n_out = n1;
#pragma unroll
            for (int p = 0; p < 9; ++p) accf[p] = acc1[p] + redB[e_loc * 9 + p];
        }

        float s = 0.f, sq = 0.f;
#pragma unroll
        for (int p = 0; p < 9; ++p) { s += accf[p]; sq += accf[p] * accf[p]; }
#pragma unroll
        for (int m = 16; m >= 1; m >>= 1) {
            s  += __shfl_xor(s, m, 64);
            sq += __shfl_xor(sq, m, 64);
        }
        float mean = s * (1.f / 288.f);
        float var = sq * (1.f / 288.f) - mean * mean;
        float rinv = rsqrtf(var + 1e-5f);
        float gs = gn_scale[e], gb = gn_bias[e];
        float ps = 0.f;
#pragma unroll
        for (int p = 0; p < 9; ++p) {
            float v = (accf[p] - mean) * rinv * gs + gb;
            ps += fmaxf(v, 0.f);
        }
        pooled[(size_t)n_out * 256 + e] = ps * (1.f / 9.f);
    }
}

// ---------------- head GEMM + spat + sym_emb + fuse matvec (k-split x2) ----------------
// block = n (128 blocks x 512 threads). t = kh*256 + e. Weights are transposed,
// k-paired bf16: one uint per lane = taps (2k, 2k+1) for its e — coalesced 4B/lane.
__global__ __launch_bounds__(512) void head_fuse(
    const float* __restrict__ pooled, const float* __restrict__ boxes,
    const unsigned short* __restrict__ head_wTb, const float* __restrict__ head_b,
    const float* __restrict__ spat_w, const float* __restrict__ spat_b,
    const float* __restrict__ sym_emb,
    const unsigned short* __restrict__ fuse_wTb, const float* __restrict__ fuse_b,
    const int* __restrict__ sym_ids, float* __restrict__ out) {
    __shared__ float pl[256];
    __shared__ float part[512];
    __shared__ float fin[256];
    int n = blockIdx.x;
    int t = threadIdx.x;
    int e = t & 255;
    int kh = t >> 8;                      // 0/1
    int sid = sym_ids[n];

    if (t < 256) pl[t] = pooled[(size_t)n * 256 + t];
    __syncthreads();

    {
        float acc = 0.f;
        const unsigned* w = (const unsigned*)head_wTb + (size_t)(kh * 64) * 256 + e;
        const float* p = pl + kh * 128;
#pragma unroll 8
        for (int kp = 0; kp < 64; ++kp) {
            unsigned u = w[kp * 256];
            acc = fmaf(p[2 * kp],     bf_lo(u), acc);
            acc = fmaf(p[2 * kp + 1], bf_hi(u), acc);
        }
        part[t] = acc;
    }
    __syncthreads();
    if (t < 256) {
        float ho = fmaxf(part[t] + part[t + 256] + head_b[t], 0.f);
        float4 sw = ((const float4*)spat_w)[t];
        float b0 = boxes[n*4+0], b1 = boxes[n*4+1], b2 = boxes[n*4+2], b3 = boxes[n*4+3];
        float sp = fmaxf(spat_b[t] + b0*sw.x + b1*sw.y + b2*sw.z + b3*sw.w, 0.f);
        fin[t] = ho + sp + sym_emb[sid * 256 + t];
    }
    __syncthreads();
    {
        float o = 0.f;
        const unsigned* w = (const unsigned*)fuse_wTb + (size_t)sid * 32768
                            + (size_t)(kh * 64) * 256 + e;
        const float* p = fin + kh * 128;
#pragma unroll 8
        for (int kp = 0; kp < 64; ++kp) {
            unsigned u = w[kp * 256];
            o = fmaf(p[2 * kp],     bf_lo(u), o);
            o = fmaf(p[2 * kp + 1], bf_hi(u), o);
        }
        part[t] = o;
    }
    __syncthreads();
    if (t < 256)
        out[(size_t)n * 256 + t] = fmaxf(part[t] + part[t + 256] + fuse_b[sid * 256 + t], 0.f);
}

extern "C" void kernel_launch(void* const* d_in, const int* in_sizes, int n_in,
                              void* d_out, int out_size, void* d_ws, size_t ws_size,
                              hipStream_t stream) {
    const float* fm      = (const float*)d_in[0];
    const float* boxes   = (const float*)d_in[1];
    const float* conv_w  = (const float*)d_in[2];
    const float* gn_s    = (const float*)d_in[3];
    const float* gn_b    = (const float*)d_in[4];
    const float* head_w  = (const float*)d_in[5];
    const float* head_b  = (const float*)d_in[6];
    const float* spat_w  = (const float*)d_in[7];
    const float* spat_b  = (const float*)d_in[8];
    const float* sym_emb = (const float*)d_in[9];
    const float* fuse_w  = (const float*)d_in[10];
    const float* fuse_b  = (const float*)d_in[11];
    const int* batch_idx = (const int*)d_in[12];
    const int* level_idx = (const int*)d_in[13];
    const int* sym_ids   = (const int*)d_in[14];
    float* outp = (float*)d_out;

    char* ws = (char*)d_ws;
    unsigned short* w8       = (unsigned short*)ws;             // [256c][256e][8] bf16: 1,048,576 B
    unsigned short* w9       = (unsigned short*)(ws + 1048576); // [256c][256e] bf16  :   131,072 B
    unsigned short* head_wTb = (unsigned short*)(ws + 1179648); // [128kp][256e][2]   :   131,072 B
    unsigned short* fuse_wTb = (unsigned short*)(ws + 1310720); // [6][128kp][256e][2]:   786,432 B
    float* roiT    = (float*)(ws + 2097152);                    // [128][9][256]      : 1,179,648 B
    float* pooled  = (float*)(ws + 3276800);                    // [128][256]         :   131,072 B

    prep_k<<<1856, 256, 0, stream>>>(conv_w, head_w, fuse_w, fm, boxes,
                                     batch_idx, level_idx,
                                     w8, w9, head_wTb, fuse_wTb, roiT);
    conv_gn_pool<<<256, 512, 0, stream>>>(roiT, w8, w9, gn_s, gn_b, pooled);
    head_fuse<<<128, 512, 0, stream>>>(pooled, boxes, head_wTb, head_b, spat_w, spat_b,
                                       sym_emb, fuse_wTb, fuse_b, sym_ids, outp);
}

// Round 12
// 248.892 us; speedup vs baseline: 1.2258x; 1.0068x over previous
//
#include <hip/hip_runtime.h>
#include <hip/hip_bf16.h>

// Pipeline: roi_align -> conv3x3(C=256->E=256 on 3x3 spatial, pad 1) -> GroupNorm(8)
//           -> ReLU -> spatial mean -> head GEMM -> +spat +sym_emb -> per-sid fuse matvec.
// Sizes: B=2, C=E=256, S=3, L=5, N=128, HMAX=128.
// 3 launches: prep -> conv_gn_pool -> head_fuse.
// R11: roi block swizzle (p*128+n instead of n*9+p) so the 9 p-blocks of one
// sample land on ONE XCD (id stride 128 === 0 mod 8) — bilinear corners of
// adjacent sample points share cache lines, now served by that XCD's L2.
// R10: c-paired s_load_dwordx2 roi + k-paired bf16 head/fuse weights.
// R5 lesson: no device fences in hot blocks. R3: transposed matvec weights.

typedef float v2f __attribute__((ext_vector_type(2)));

__device__ __forceinline__ float bf_lo(unsigned u) { return __uint_as_float(u << 16); }
__device__ __forceinline__ float bf_hi(unsigned u) { return __uint_as_float(u & 0xffff0000u); }
__device__ __forceinline__ unsigned short f2bf(float f) {
    __hip_bfloat16 h = __float2bfloat16(f);
    return *(unsigned short*)&h;
}

// ---------------- fused prep kernel ----------------
// grid.x: [0,256)    w_prep (block=c, thread=e)
//         [256,704)  t7     (448 tiles: head_w + 6x fuse_w -> transposed k-paired bf16)
//         [704,1856) roi    (block q = p*128 + n  [XCD-swizzled], thread=c)
__global__ __launch_bounds__(256) void prep_k(
    const float* __restrict__ conv_w,
    const float* __restrict__ head_w, const float* __restrict__ fuse_w,
    const float* __restrict__ fm, const float* __restrict__ boxes,
    const int* __restrict__ batch_idx, const int* __restrict__ level_idx,
    unsigned short* __restrict__ w8, unsigned short* __restrict__ w9,
    unsigned short* __restrict__ head_wTb, unsigned short* __restrict__ fuse_wTb,
    float* __restrict__ roiT) {
    int blk = blockIdx.x;
    int t = threadIdx.x;

    if (blk < 256) {
        // conv weight repack: [e][c][9] f32 -> w8[c][e][8] + w9[c][e] bf16
        int c = blk, e = t;
        const float* src = conv_w + ((size_t)e * 256 + c) * 9;
        unsigned short tmp[8];
#pragma unroll
        for (int k = 0; k < 8; ++k) tmp[k] = f2bf(src[k]);
        ((uint4*)w8)[(size_t)c * 256 + e] = *(const uint4*)tmp;
        w9[(size_t)c * 256 + e] = f2bf(src[8]);
        return;
    }

    if (blk < 704) {
        // 32x32 tiled transpose of head_w (z=0) / fuse_w (z=1..6).
        // Output: k-paired bf16 — ushort index ((k>>1)*256 + e)*2 + (k&1).
        __shared__ float tile[32][33];
        int q = blk - 256;
        int z = q >> 6;
        int rem = q & 63;
        int bx = (rem & 7) * 32, by = (rem >> 3) * 32;
        const float* in = (z == 0) ? head_w : fuse_w + (size_t)(z - 1) * 65536;
        unsigned short* out = (z == 0) ? head_wTb : fuse_wTb + (size_t)(z - 1) * 65536;
        int tx = t & 31, ty = t >> 5;
#pragma unroll
        for (int i = 0; i < 32; i += 8)
            tile[ty + i][tx] = in[(size_t)(by + ty + i) * 256 + bx + tx];
        __syncthreads();
#pragma unroll
        for (int i = 0; i < 32; i += 8) {
            int k = bx + ty + i;          // transposed row (original col)
            int e = by + tx;
            out[(size_t)((k >> 1) * 256 + e) * 2 + (k & 1)] = f2bf(tile[tx][ty + i]);
        }
        return;
    }

    // ROI align: roiT[n][p][c]. Block decode q = p*128 + n: all 9 p-blocks of a
    // sample share an XCD (stride 128 === 0 mod 8) -> shared bilinear lines in L2.
    {
        int q = blk - 704;
        int n = q & 127, p = q >> 7;
        int i = p / 3, j = p % 3;
        int c = t;

        int lvl = level_idx[n];
        int b = batch_idx[n];
        const float sizes[5]  = {128.f, 64.f, 32.f, 16.f, 8.f};
        const float invstr[5] = {1.f/8.f, 1.f/16.f, 1.f/32.f, 1.f/64.f, 1.f/128.f};
        float scale = invstr[lvl];
        float hv = sizes[lvl];

        float x1 = boxes[n*4+0] * scale, y1 = boxes[n*4+1] * scale;
        float x2 = boxes[n*4+2] * scale, y2 = boxes[n*4+3] * scale;
        float rw = fmaxf(x2 - x1, 1.f), rh = fmaxf(y2 - y1, 1.f);
        float x = x1 + (((float)j + 0.5f) / 3.f) * rw;
        float y = y1 + (((float)i + 0.5f) / 3.f) * rh;

        bool valid = (y > -1.f) && (y < hv) && (x > -1.f) && (x < hv);
        float yc = fminf(fmaxf(y, 0.f), hv - 1.f);
        float xc = fminf(fmaxf(x, 0.f), hv - 1.f);
        int y0 = (int)floorf(yc), x0 = (int)floorf(xc);
        int hi = (int)(hv - 1.f);
        int y1i = min(y0 + 1, hi), x1i = min(x0 + 1, hi);
        float ly = yc - (float)y0, lx = xc - (float)x0;

        const float* base = fm + (((size_t)lvl * 2 + b) * 256 + c) * (128 * 128);
        float v00 = base[y0 * 128 + x0];
        float v01 = base[y0 * 128 + x1i];
        float v10 = base[y1i * 128 + x0];
        float v11 = base[y1i * 128 + x1i];
        float v = (1.f - ly) * (1.f - lx) * v00 + (1.f - ly) * lx * v01 +
                  ly * (1.f - lx) * v10 + ly * lx * v11;
        roiT[((size_t)n * 9 + p) * 256 + c] = valid ? v : 0.f;
    }
}

// ---------------- conv3x3 + GroupNorm + ReLU + spatial-mean ----------------
// Block = (n-pair, e-quarter): 256 blocks x 512 threads.
// thread: e_loc = t&63, ch = t>>6 (8 c-slices of 32 channels, c in pairs).
// Sample pair packed in v2f lanes (.x = n0, .y = n1) -> v_pk_fma_f32; roi values
// wave-uniform -> s_load_dwordx2 over adjacent c. GN group = e/32: 32-lane halves.
__global__ __launch_bounds__(512, 2) void conv_gn_pool(
    const float* __restrict__ roiT,
    const unsigned short* __restrict__ w8, const unsigned short* __restrict__ w9,
    const float* __restrict__ gn_scale, const float* __restrict__ gn_bias,
    float* __restrict__ pooled) {
    __shared__ float redA[4 * 64 * 9];
    __shared__ float redB[4 * 64 * 9];

    int np = blockIdx.x >> 2;             // 0..63 sample pair
    int eq = blockIdx.x & 3;
    int n0 = np * 2, n1 = n0 + 1;
    int t = threadIdx.x;
    int e_loc = t & 63;
    int ch = __builtin_amdgcn_readfirstlane(t >> 6);   // wave-uniform 0..7
    int e = eq * 64 + e_loc;

    const float* r0 = roiT + (size_t)n0 * 2304;   // [p][c]
    const float* r1 = roiT + (size_t)n1 * 2304;

    v2f acc[9];
#pragma unroll
    for (int p = 0; p < 9; ++p) acc[p] = (v2f)(0.f);

    int c0 = ch * 32;
#pragma unroll 2
    for (int c = c0; c < c0 + 32; c += 2) {
        // wave-uniform float2 roi loads (adjacent c, 8B-aligned) -> s_load_dwordx2
        v2f q0[9], q1[9];                 // q0: sample0 (c, c+1), q1: sample1
#pragma unroll
        for (int jj = 0; jj < 9; ++jj) {
            q0[jj] = *(const v2f*)(r0 + jj * 256 + c);
            q1[jj] = *(const v2f*)(r1 + jj * 256 + c);
        }
        // sample-packed uniform pairs per c
        v2f rc0[9], rc1[9];
#pragma unroll
        for (int jj = 0; jj < 9; ++jj) {
            rc0[jj].x = q0[jj].x; rc0[jj].y = q1[jj].x;   // channel c
            rc1[jj].x = q0[jj].y; rc1[jj].y = q1[jj].y;   // channel c+1
        }
#pragma unroll
        for (int cc = 0; cc < 2; ++cc) {
            const v2f* r = cc ? rc1 : rc0;
            int cw = c + cc;
            uint4 wa4 = ((const uint4*)w8)[(size_t)cw * 256 + e];
            float wv[9];
            wv[0] = bf_lo(wa4.x); wv[1] = bf_hi(wa4.x);
            wv[2] = bf_lo(wa4.y); wv[3] = bf_hi(wa4.y);
            wv[4] = bf_lo(wa4.z); wv[5] = bf_hi(wa4.z);
            wv[6] = bf_lo(wa4.w); wv[7] = bf_hi(wa4.w);
            wv[8] = bf_lo((unsigned)w9[(size_t)cw * 256 + e]);
#pragma unroll
            for (int ky = 0; ky < 3; ++ky) {
#pragma unroll
                for (int kx = 0; kx < 3; ++kx) {
                    v2f w2;
                    w2.x = wv[ky * 3 + kx]; w2.y = wv[ky * 3 + kx];
#pragma unroll
                    for (int oy = 0; oy < 3; ++oy) {
                        int iy = oy + ky - 1;
                        if (iy < 0 || iy > 2) continue;
#pragma unroll
                        for (int ox = 0; ox < 3; ++ox) {
                            int ix = ox + kx - 1;
                            if (ix < 0 || ix > 2) continue;
                            int o = oy * 3 + ox, in = iy * 3 + ix;
                            acc[o] = w2 * r[in] + acc[o];   // -> v_pk_fma_f32
                        }
                    }
                }
            }
        }
    }

    float acc0[9], acc1[9];
#pragma unroll
    for (int p = 0; p < 9; ++p) { acc0[p] = acc[p].x; acc1[p] = acc[p].y; }

    // tree-reduce 8 c-slices into ch==0 (sample0) / ch==1 (sample1)
    if (ch >= 4) {
#pragma unroll
        for (int p = 0; p < 9; ++p) {
            redA[((ch - 4) * 64 + e_loc) * 9 + p] = acc0[p];
            redB[((ch - 4) * 64 + e_loc) * 9 + p] = acc1[p];
        }
    }
    __syncthreads();
    if (ch < 4) {
#pragma unroll
        for (int p = 0; p < 9; ++p) {
            acc0[p] += redA[(ch * 64 + e_loc) * 9 + p];
            acc1[p] += redB[(ch * 64 + e_loc) * 9 + p];
        }
    }
    __syncthreads();
    if (ch >= 2 && ch < 4) {
#pragma unroll
        for (int p = 0; p < 9; ++p) {
            redA[((ch - 2) * 64 + e_loc) * 9 + p] = acc0[p];
            redB[((ch - 2) * 64 + e_loc) * 9 + p] = acc1[p];
        }
    }
    __syncthreads();
    if (ch < 2) {
#pragma unroll
        for (int p = 0; p < 9; ++p) {
            acc0[p] += redA[(ch * 64 + e_loc) * 9 + p];
            acc1[p] += redB[(ch * 64 + e_loc) * 9 + p];
        }
    }
    __syncthreads();
    if (ch == 1) {
#pragma unroll
        for (int p = 0; p < 9; ++p) redA[e_loc * 9 + p] = acc0[p];
    }
    if (ch == 0) {
#pragma unroll
        for (int p = 0; p < 9; ++p) redB[e_loc * 9 + p] = acc1[p];
    }
    __syncthreads();

    if (ch < 2) {
        float accf[9];
        int n_out;
        if (ch == 0) {
            n_out = n0;
#pragma unroll
            for (int p = 0; p < 9; ++p) accf[p] = acc0[p] + redA[e_loc * 9 + p];
        } else {
            n_out = n1;
#pragma unroll
            for (int p = 0; p < 9; ++p) accf[p] = acc1[p] + redB[e_loc * 9 + p];
        }

        float s = 0.f, sq = 0.f;
#pragma unroll
        for (int p = 0; p < 9; ++p) { s += accf[p]; sq += accf[p] * accf[p]; }
#pragma unroll
        for (int m = 16; m >= 1; m >>= 1) {
            s  += __shfl_xor(s, m, 64);
            sq += __shfl_xor(sq, m, 64);
        }
        float mean = s * (1.f / 288.f);
        float var = sq * (1.f / 288.f) - mean * mean;
        float rinv = rsqrtf(var + 1e-5f);
        float gs = gn_scale[e], gb = gn_bias[e];
        float ps = 0.f;
#pragma unroll
        for (int p = 0; p < 9; ++p) {
            float v = (accf[p] - mean) * rinv * gs + gb;
            ps += fmaxf(v, 0.f);
        }
        pooled[(size_t)n_out * 256 + e] = ps * (1.f / 9.f);
    }
}

// ---------------- head GEMM + spat + sym_emb + fuse matvec (k-split x2) ----------------
// block = n (128 blocks x 512 threads). t = kh*256 + e. Weights are transposed,
// k-paired bf16: one uint per lane = taps (2k, 2k+1) for its e — coalesced 4B/lane.
__global__ __launch_bounds__(512) void head_fuse(
    const float* __restrict__ pooled, const float* __restrict__ boxes,
    const unsigned short* __restrict__ head_wTb, const float* __restrict__ head_b,
    const float* __restrict__ spat_w, const float* __restrict__ spat_b,
    const float* __restrict__ sym_emb,
    const unsigned short* __restrict__ fuse_wTb, const float* __restrict__ fuse_b,
    const int* __restrict__ sym_ids, float* __restrict__ out) {
    __shared__ float pl[256];
    __shared__ float part[512];
    __shared__ float fin[256];
    int n = blockIdx.x;
    int t = threadIdx.x;
    int e = t & 255;
    int kh = t >> 8;                      // 0/1
    int sid = sym_ids[n];

    if (t < 256) pl[t] = pooled[(size_t)n * 256 + t];
    __syncthreads();

    {
        float acc = 0.f;
        const unsigned* w = (const unsigned*)head_wTb + (size_t)(kh * 64) * 256 + e;
        const float* p = pl + kh * 128;
#pragma unroll 8
        for (int kp = 0; kp < 64; ++kp) {
            unsigned u = w[kp * 256];
            acc = fmaf(p[2 * kp],     bf_lo(u), acc);
            acc = fmaf(p[2 * kp + 1], bf_hi(u), acc);
        }
        part[t] = acc;
    }
    __syncthreads();
    if (t < 256) {
        float ho = fmaxf(part[t] + part[t + 256] + head_b[t], 0.f);
        float4 sw = ((const float4*)spat_w)[t];
        float b0 = boxes[n*4+0], b1 = boxes[n*4+1], b2 = boxes[n*4+2], b3 = boxes[n*4+3];
        float sp = fmaxf(spat_b[t] + b0*sw.x + b1*sw.y + b2*sw.z + b3*sw.w, 0.f);
        fin[t] = ho + sp + sym_emb[sid * 256 + t];
    }
    __syncthreads();
    {
        float o = 0.f;
        const unsigned* w = (const unsigned*)fuse_wTb + (size_t)sid * 32768
                            + (size_t)(kh * 64) * 256 + e;
        const float* p = fin + kh * 128;
#pragma unroll 8
        for (int kp = 0; kp < 64; ++kp) {
            unsigned u = w[kp * 256];
            o = fmaf(p[2 * kp],     bf_lo(u), o);
            o = fmaf(p[2 * kp + 1], bf_hi(u), o);
        }
        part[t] = o;
    }
    __syncthreads();
    if (t < 256)
        out[(size_t)n * 256 + t] = fmaxf(part[t] + part[t + 256] + fuse_b[sid * 256 + t], 0.f);
}

extern "C" void kernel_launch(void* const* d_in, const int* in_sizes, int n_in,
                              void* d_out, int out_size, void* d_ws, size_t ws_size,
                              hipStream_t stream) {
    const float* fm      = (const float*)d_in[0];
    const float* boxes   = (const float*)d_in[1];
    const float* conv_w  = (const float*)d_in[2];
    const float* gn_s    = (const float*)d_in[3];
    const float* gn_b    = (const float*)d_in[4];
    const float* head_w  = (const float*)d_in[5];
    const float* head_b  = (const float*)d_in[6];
    const float* spat_w  = (const float*)d_in[7];
    const float* spat_b  = (const float*)d_in[8];
    const float* sym_emb = (const float*)d_in[9];
    const float* fuse_w  = (const float*)d_in[10];
    const float* fuse_b  = (const float*)d_in[11];
    const int* batch_idx = (const int*)d_in[12];
    const int* level_idx = (const int*)d_in[13];
    const int* sym_ids   = (const int*)d_in[14];
    float* outp = (float*)d_out;

    char* ws = (char*)d_ws;
    unsigned short* w8       = (unsigned short*)ws;             // [256c][256e][8] bf16: 1,048,576 B
    unsigned short* w9       = (unsigned short*)(ws + 1048576); // [256c][256e] bf16  :   131,072 B
    unsigned short* head_wTb = (unsigned short*)(ws + 1179648); // [128kp][256e][2]   :   131,072 B
    unsigned short* fuse_wTb = (unsigned short*)(ws + 1310720); // [6][128kp][256e][2]:   786,432 B
    float* roiT    = (float*)(ws + 2097152);                    // [128][9][256]      : 1,179,648 B
    float* pooled  = (float*)(ws + 3276800);                    // [128][256]         :   131,072 B

    prep_k<<<1856, 256, 0, stream>>>(conv_w, head_w, fuse_w, fm, boxes,
                                     batch_idx, level_idx,
                                     w8, w9, head_wTb, fuse_wTb, roiT);
    conv_gn_pool<<<256, 512, 0, stream>>>(roiT, w8, w9, gn_s, gn_b, pooled);
    head_fuse<<<128, 512, 0, stream>>>(pooled, boxes, head_wTb, head_b, spat_w, spat_b,
                                       sym_emb, fuse_wTb, fuse_b, sym_ids, outp);
}